// Round 14
// baseline (260.200 us; speedup 1.0000x reference)
//
#include <hip/hip_runtime.h>

// ---------------------------------------------------------------------------
// MLA prefill (B=4, S=2048, D=768, H=8, q_rank=kv_rank=rope=64, nope=32, v=96)
// Round 23: k3 v10 — wave owns 64 q (groups A-D), block = 256 q, grid
// (8,8,4) = 1 block/CU. Each K/V-fragment LDS read feeds 4 MFMAs (was 2);
// staging per CU halves (1 block stages, not 2). LDS instr/CU/tile ~272->
// ~152 b128. k3 shown LDS-pipe-bound (~76% by instruction count + conflict
// cycles; VALU cut was time-neutral). LDS 63488B, ~230 VGPR, 1 wave/SIMD.
// cvt_pk P-pack kept. k1/k2b/k5a/k5b/prep = round-22 exact (248.2us).
// ---------------------------------------------------------------------------

#define DEV static __device__ __forceinline__
typedef unsigned short ushort_t;
typedef __attribute__((ext_vector_type(8))) short bf8_t;
typedef __attribute__((ext_vector_type(4))) float f4_t;

DEV float bf2f(unsigned int u) {
    union { float f; unsigned int i; } x; x.i = u << 16; return x.f;
}
DEV ushort_t f2bf(float f) {
    union { float f; unsigned int u; } x; x.f = f;
    unsigned int u = x.u;
    return (ushort_t)((u + 0x7fffu + ((u >> 16) & 1u)) >> 16);
}
DEV unsigned cvtpk_bf16(float lo, float hi) {   // packed f32x2 -> bf16x2, RNE
    unsigned r;
    asm("v_cvt_pk_bf16_f32 %0, %1, %2" : "=v"(r) : "v"(lo), "v"(hi));
    return r;
}
DEV float ldin(const void* p, size_t i, int isbf) {
    return isbf ? bf2f(((const ushort_t*)p)[i]) : ((const float*)p)[i];
}
DEV float fexp2(float x) {
#if __has_builtin(__builtin_amdgcn_exp2f)
    return __builtin_amdgcn_exp2f(x);
#else
    return exp2f(x);
#endif
}
DEV int get_isbf(const void* nw) {
    return ((((const unsigned int*)nw)[0] & 0xffffu) != 0u) ? 1 : 0;
}

constexpr int   TOK   = 4 * 2048;                         // 8192 tokens
constexpr float EPSF  = 1e-6f;
// Q' carries SCALE*log2(e) so softmax uses native exp2
constexpr float QSCALE = (float)(0.10206207261596575 * 1.4426950408889634);
constexpr float L2_10000_OVER_32 = 0.4152410118609203f;   // log2(10000)/32

// workspace layout (float offsets)
constexpr size_t OFF_WOT   = 0;                 // wo bf16 [768][768]
constexpr size_t OFF_WKVAT = 589824;            // wkv_a bf16 [128][768] (k1 B)
constexpr size_t OFF_WQAT  = 688128;            // wq_a bf16 [64][768] (k1 qn B)
constexpr size_t OFF_WQBT  = 737280;            // wq_b bf16 [768][64] (k2b B)
constexpr size_t OFF_QAF   = 786432;            // q_absorbT*QSCALE bf16 [8][64][32]
constexpr size_t OFF_OAT   = 802816;            // out_absorbT [8][64][96] fp32
constexpr size_t OFF_QLN   = 851968;
constexpr size_t OFF_KVLN  = 852032;
constexpr size_t OFF_NW    = 852096;
constexpr size_t OFF_FLAG  = 852864;            // (unused since round 12)
constexpr size_t OFF_CTXF  = 852880;            // ctx bf16 [8192][768]; qn bf16 [8192][64] before k3
constexpr size_t OFF_SRCBF = 3998608;           // (dead since round 21)
constexpr size_t OFF_KBF   = 7144336;           // K' bf16 [4][2048][128]
constexpr size_t OFF_VTB   = 7668624;           // V^T bf16 [4][64][2048]
constexpr size_t OFF_QBF   = 7930768;           // Q' bf16 [4][8][2048][128]; y bf16 [8192][768] after k3
constexpr size_t OFF_ROPE  = 12125072;          // rope table float2 [2048][32]

// prep 1D-grid segment offsets (256-thr blocks)
constexpr int PB0 = 2304;            // wo copy        [0, 2304)
constexpr int PB1 = PB0 + 384;       // wkv_a          [2304, 2688)
constexpr int PB2 = PB1 + 192;       // wq_a           [2688, 2880)
constexpr int PB3 = PB2 + 192;       // wq_b           [2880, 3072)
constexpr int PB4 = PB3 + 64;        // q_absorbT      [3072, 3136)
constexpr int PB5 = PB4 + 192;       // out_absorbT    [3136, 3328)
constexpr int PB6 = PB5 + 4;         // norm vectors   [3328, 3332)
constexpr int PB7 = PB6 + 256;       // rope table     [3332, 3588)

// ---------------------------------------------------------------------------
__global__ __launch_bounds__(256) void prep_k(
    const void* __restrict__ wq_a, const void* __restrict__ q_ln,
    const void* __restrict__ wq_b, const void* __restrict__ wkv_a,
    const void* __restrict__ kv_ln, const void* __restrict__ wkv_b,
    const void* __restrict__ wo, const void* __restrict__ nw,
    float* __restrict__ ws)
{
    const int isbf = get_isbf(nw);
    const int bid = blockIdx.x;
    const int tid = threadIdx.x;
    if (bid < PB0) {        // wo -> bf16 straight copy
        int i = bid * 256 + tid;
        ushort_t* wob = (ushort_t*)(ws + OFF_WOT);
        wob[i] = isbf ? ((const ushort_t*)wo)[i] : f2bf(((const float*)wo)[i]);
    } else if (bid < PB1) { // wkv_a bf16 straight [128][768]
        int i = (bid - PB0) * 256 + tid;
        ushort_t* d = (ushort_t*)(ws + OFF_WKVAT);
        d[i] = isbf ? ((const ushort_t*)wkv_a)[i] : f2bf(((const float*)wkv_a)[i]);
    } else if (bid < PB2) { // wq_a bf16 straight [64][768]
        int i = (bid - PB1) * 256 + tid;
        ushort_t* d = (ushort_t*)(ws + OFF_WQAT);
        d[i] = isbf ? ((const ushort_t*)wq_a)[i] : f2bf(((const float*)wq_a)[i]);
    } else if (bid < PB3) { // wq_b bf16 straight [768][64]
        int i = (bid - PB2) * 256 + tid;
        ushort_t* d = (ushort_t*)(ws + OFF_WQBT);
        d[i] = isbf ? ((const ushort_t*)wq_b)[i] : f2bf(((const float*)wq_b)[i]);
    } else if (bid < PB4) { // q_absorbT * QSCALE bf16 [8][r=64][d=32]
        int i = (bid - PB3) * 256 + tid;
        int h = i >> 11, rem = i & 2047, r = rem >> 5, d = rem & 31;
        ushort_t* dst = (ushort_t*)(ws + OFF_QAF);
        dst[i] = f2bf(ldin(wkv_b, (size_t)(h * 128 + d) * 64 + r, isbf) * QSCALE);
    } else if (bid < PB5) { // out_absorbT [h][r][v] fp32
        int i = (bid - PB4) * 256 + tid;
        int h = i / 6144, rem = i - h * 6144;
        int r = rem / 96, v = rem - r * 96;
        ws[OFF_OAT + i] = ldin(wkv_b, (size_t)h * 8192 + 2048 + v * 64 + r, isbf);
    } else if (bid < PB6) { // norm vectors (896 elements)
        int i = (bid - PB5) * 256 + tid;
        if (i < 64)             ws[OFF_QLN + i]       = ldin(q_ln, i, isbf);
        else if (i < 128)       ws[OFF_KVLN + i - 64] = ldin(kv_ln, i - 64, isbf);
        else if (i < 128 + 768) ws[OFF_NW + i - 128]  = ldin(nw, i - 128, isbf);
    } else {                // rope table [pos][p] = (cos, sin)
        int i = (bid - PB6) * 256 + tid;
        int pos = i >> 5, p = i & 31;
        float inv = exp2f(-(float)p * L2_10000_OVER_32);
        float ang = (float)pos * inv;
        float2* tab = (float2*)(ws + OFF_ROPE);
        tab[i] = make_float2(cosf(ang), sinf(ang));
    }
}

// ---------------------------------------------------------------------------
// k1 v3: MFMA ckv GEMM + epilogue + merged qn pass (waves 0-1, from sA).
// ---------------------------------------------------------------------------
__global__ __launch_bounds__(512) void k1_ckv(
    const void* __restrict__ src, const void* __restrict__ nw,
    const float* __restrict__ ws,
    ushort_t* __restrict__ Kbf, ushort_t* __restrict__ VTbf,
    ushort_t* __restrict__ qn_all)
{
    const ushort_t* wkvab = (const ushort_t*)(ws + OFF_WKVAT);  // [128][768]
    const ushort_t* wqab  = (const ushort_t*)(ws + OFF_WQAT);   // [64][768]
    const float* kvln  = ws + OFF_KVLN;
    const float* qln   = ws + OFF_QLN;
    const float2* tab  = (const float2*)(ws + OFF_ROPE);
    const int isbf = get_isbf(nw);
    __shared__ __align__(16) ushort_t sA[32 * 776];
    __shared__ __align__(16) float ckv[32][132];
    int j = threadIdx.x;
    int t0 = blockIdx.x * 32;
    int w = j >> 6, lane = j & 63;
    int tl = lane & 15, qd = lane >> 4;

    {   // stage A: src[t0..t0+31][0..767] -> sA bf16 (stride 776)
        for (int e = j; e < 32 * 96; e += 512) {
            int row = e / 96, c8 = e - row * 96;
            size_t off = (size_t)(t0 + row) * 768 + c8 * 8;
            if (isbf) {
                uint4 v = *(const uint4*)((const ushort_t*)src + off);
                *(uint4*)(sA + row * 776 + c8 * 8) = v;
            } else {
                const float4* p = (const float4*)((const float*)src + off);
                float4 f0 = p[0], f1 = p[1];
                ushort_t tmp[8] = {f2bf(f0.x), f2bf(f0.y), f2bf(f0.z), f2bf(f0.w),
                                   f2bf(f1.x), f2bf(f1.y), f2bf(f1.z), f2bf(f1.w)};
                uint4 v = *(const uint4*)tmp;
                *(uint4*)(sA + row * 776 + c8 * 8) = v;
            }
        }
    }
    __syncthreads();
    {   // GEMM: ckv[32][128] = A @ wkv_a^T, wave w owns cols w*16..w*16+15
        f4_t acc[2];
        acc[0] = (f4_t){0.f, 0.f, 0.f, 0.f};
        acc[1] = (f4_t){0.f, 0.f, 0.f, 0.f};
        const ushort_t* bp = wkvab + (size_t)(w * 16 + tl) * 768 + qd * 8;
#pragma unroll 4
        for (int ks = 0; ks < 24; ++ks) {
            bf8_t b  = *(const bf8_t*)(bp + ks * 32);
            bf8_t a0 = *(const bf8_t*)(sA + tl * 776 + ks * 32 + qd * 8);
            bf8_t a1 = *(const bf8_t*)(sA + (16 + tl) * 776 + ks * 32 + qd * 8);
            acc[0] = __builtin_amdgcn_mfma_f32_16x16x32_bf16(a0, b, acc[0], 0, 0, 0);
            acc[1] = __builtin_amdgcn_mfma_f32_16x16x32_bf16(a1, b, acc[1], 0, 0, 0);
        }
#pragma unroll
        for (int mt = 0; mt < 2; ++mt)
#pragma unroll
            for (int r = 0; r < 4; ++r)
                ckv[mt * 16 + qd * 4 + r][w * 16 + tl] = acc[mt][r];
    }
    __syncthreads();

    if (j < 256) {
        int tt = j >> 3, l = j & 7;
        float ss = 0.f;
#pragma unroll
        for (int i = 0; i < 8; ++i) { float v = ckv[tt][l * 8 + i]; ss += v * v; }
        ss += __shfl_xor(ss, 1); ss += __shfl_xor(ss, 2); ss += __shfl_xor(ss, 4);
        float rs = rsqrtf(ss * (1.f / 64.f) + EPSF);
        size_t base = (size_t)(t0 + tt) * 128;
        ushort_t kb[8];
        float clw[8];
#pragma unroll
        for (int i = 0; i < 8; ++i) {
            int o2 = l * 8 + i;
            float cl = ckv[tt][o2] * rs;
            if (isbf) cl = bf2f(f2bf(cl));   // reference: .astype(bf16) before *w
            clw[i] = cl * kvln[o2];
            kb[i] = f2bf(clw[i]);
        }
        uint4 pack;
        pack.x = kb[0] | ((unsigned)kb[1] << 16); pack.y = kb[2] | ((unsigned)kb[3] << 16);
        pack.z = kb[4] | ((unsigned)kb[5] << 16); pack.w = kb[6] | ((unsigned)kb[7] << 16);
        *(uint4*)&Kbf[base + l * 8] = pack;
        int pos = (t0 + tt) & 2047;
        ushort_t r0[4], r1[4];
#pragma unroll
        for (int i = 0; i < 4; ++i) {
            int p = l * 4 + i;
            float2 cssn = tab[pos * 32 + p];
            float e = ckv[tt][64 + 2 * p], od = ckv[tt][64 + 2 * p + 1];
            r0[i] = f2bf(e * cssn.x - od * cssn.y);
            r1[i] = f2bf(od * cssn.x + e * cssn.y);
        }
        uint2 p0, p1;
        p0.x = r0[0] | ((unsigned)r0[1] << 16); p0.y = r0[2] | ((unsigned)r0[3] << 16);
        p1.x = r1[0] | ((unsigned)r1[1] << 16); p1.y = r1[2] | ((unsigned)r1[3] << 16);
        *(uint2*)&Kbf[base + 64 + l * 4] = p0;
        *(uint2*)&Kbf[base + 96 + l * 4] = p1;
#pragma unroll
        for (int i = 0; i < 8; ++i) ckv[tt][l * 8 + i] = clw[i];
    }
    __syncthreads();
    if (j < 256) {   // VT[b][r][t] = c_lat_n[t][r]
        int t = j & 31, rb = (j >> 5) * 8;
        int bb = t0 >> 11, col = (t0 & 2047) + t;
#pragma unroll
        for (int i = 0; i < 8; ++i) {
            int r = rb + i;
            VTbf[((size_t)(bb * 64 + r)) * 2048 + col] = f2bf(ckv[t][r]);
        }
    }
    __syncthreads();   // ckv free for reuse as qn bounce
    if (w < 2) {       // merged qn pass: wave w -> tokens t0 + w*16 .. +15
        f4_t C1[4];
#pragma unroll
        for (int nt = 0; nt < 4; ++nt) C1[nt] = (f4_t){0.f, 0.f, 0.f, 0.f};
        const ushort_t* ap = sA + (size_t)(w * 16 + tl) * 776 + qd * 8;
#pragma unroll 4
        for (int ks = 0; ks < 24; ++ks) {
            bf8_t a = *(const bf8_t*)(ap + ks * 32);
#pragma unroll
            for (int nt = 0; nt < 4; ++nt) {
                bf8_t bfr = *(const bf8_t*)(wqab + (size_t)(nt * 16 + tl) * 768 + ks * 32 + qd * 8);
                C1[nt] = __builtin_amdgcn_mfma_f32_16x16x32_bf16(a, bfr, C1[nt], 0, 0, 0);
            }
        }
        float rsv[4];
#pragma unroll
        for (int r = 0; r < 4; ++r) {
            float s = C1[0][r] * C1[0][r] + C1[1][r] * C1[1][r]
                    + C1[2][r] * C1[2][r] + C1[3][r] * C1[3][r];
            s += __shfl_xor(s, 1); s += __shfl_xor(s, 2);
            s += __shfl_xor(s, 4); s += __shfl_xor(s, 8);
            rsv[r] = rsqrtf(s * (1.f / 64.f) + EPSF);
        }
        float qlnv[4];
#pragma unroll
        for (int nt = 0; nt < 4; ++nt) qlnv[nt] = qln[nt * 16 + tl];
        ushort_t* tmpn = (ushort_t*)&ckv[0][0] + w * 1152;
#pragma unroll
        for (int nt = 0; nt < 4; ++nt)
#pragma unroll
            for (int r = 0; r < 4; ++r) {
                float v = C1[nt][r] * rsv[r];
                if (isbf) v = bf2f(f2bf(v));  // .astype(bf16) before *w
                tmpn[(qd * 4 + r) * 72 + nt * 16 + tl] = f2bf(v * qlnv[nt]);
            }
#pragma unroll
        for (int i = 0; i < 2; ++i) {
            int e = i * 64 + lane;
            int row = e >> 3, ch = e & 7;
            uint4 v = *(const uint4*)(tmpn + row * 72 + ch * 8);
            *(uint4*)(qn_all + (size_t)(t0 + w * 16 + row) * 64 + ch * 8) = v;
        }
    }
}

// ---------------------------------------------------------------------------
// k2b: Q' = rope/absorb(qn @ wq_b^T). Block = 32 tok x 384 cols (4 heads),
// 512 thr (8 waves); wave = 16 tok x 1 head. wq_b staged once in LDS.
// ---------------------------------------------------------------------------
__global__ __launch_bounds__(512) void k2b_q(
    const float* __restrict__ ws, const ushort_t* __restrict__ qn_all,
    ushort_t* __restrict__ Qbf)
{
    const ushort_t* wqbb = (const ushort_t*)(ws + OFF_WQBT);   // [768][64]
    const ushort_t* qabs = (const ushort_t*)(ws + OFF_QAF);    // [8][64][32] *QSCALE
    const float2*   tab  = (const float2*)(ws + OFF_ROPE);

    __shared__ __align__(16) ushort_t sB[384 * 72];    // 27648 sh
    __shared__ __align__(16) ushort_t sA[32 * 72];     //  2304 sh
    __shared__ __align__(16) ushort_t PW[8 * 2816];    // per wave: qn 640 + qf 2176
    int j = threadIdx.x;
    int bx = blockIdx.x;
    int t0 = (bx >> 1) * 32;
    int colh = (bx & 1) * 384;
    int w = j >> 6, lane = j & 63;
    int tl = lane & 15, qd = lane >> 4;
    int mt = w & 1, hh = w >> 1;
    int h = (bx & 1) * 4 + hh;
    ushort_t* qnb = PW + w * 2816;
    ushort_t* qf  = qnb + 640;
    int tokw = t0 + mt * 16;

    {   // stage B: wq_b rows colh..colh+383 x 64 k (384 x 8 uint4)
        for (int e = j; e < 384 * 8; e += 512) {
            int rr = e >> 3, ch = e & 7;
            uint4 v = *(const uint4*)(wqbb + (size_t)(colh + rr) * 64 + ch * 8);
            *(uint4*)(sB + rr * 72 + ch * 8) = v;
        }
    }
    if (j < 256) {  // stage A: qn rows t0..t0+31 x 64
        int rr = j >> 3, ch = j & 7;
        uint4 v = *(const uint4*)(qn_all + (size_t)(t0 + rr) * 64 + ch * 8);
        *(uint4*)(sA + rr * 72 + ch * 8) = v;
    }
    __syncthreads();

    bf8_t A2[2];
#pragma unroll
    for (int ks = 0; ks < 2; ++ks)
        A2[ks] = *(const bf8_t*)(sA + (mt * 16 + tl) * 72 + ks * 32 + qd * 8);

    // rope cos/sin preload, scaled by QSCALE
    float csv[4][4], snv[4][4];
#pragma unroll
    for (int nt2 = 0; nt2 < 4; ++nt2) {
        int p = (nt2 * 16 + tl) >> 1;
#pragma unroll
        for (int r = 0; r < 4; ++r) {
            int pos = (tokw + qd * 4 + r) & 2047;
            float2 t = tab[pos * 32 + p];
            csv[nt2][r] = t.x * QSCALE;
            snv[nt2][r] = t.y * QSCALE;
        }
    }
    const bool evn = !(tl & 1);
    int bb = tokw >> 11, pos0 = tokw & 2047;

    // GEMM2: C2[6] = qn @ wq_b^T (head h cols), B from LDS
    f4_t C2[6];
#pragma unroll
    for (int nt = 0; nt < 6; ++nt) C2[nt] = (f4_t){0.f, 0.f, 0.f, 0.f};
#pragma unroll
    for (int nt = 0; nt < 6; ++nt)
#pragma unroll
        for (int ks = 0; ks < 2; ++ks) {
            bf8_t bfr = *(const bf8_t*)(sB + (hh * 96 + nt * 16 + tl) * 72 + ks * 32 + qd * 8);
            C2[nt] = __builtin_amdgcn_mfma_f32_16x16x32_bf16(A2[ks], bfr, C2[nt], 0, 0, 0);
        }
    // q_nope bounce -> A-frag for absorb
#pragma unroll
    for (int nt = 0; nt < 2; ++nt)
#pragma unroll
        for (int r = 0; r < 4; ++r)
            qnb[(qd * 4 + r) * 40 + nt * 16 + tl] = f2bf(C2[nt][r]);
    bf8_t an = *(const bf8_t*)(qnb + tl * 40 + qd * 8);
    f4_t C3[4];
#pragma unroll
    for (int nt = 0; nt < 4; ++nt) C3[nt] = (f4_t){0.f, 0.f, 0.f, 0.f};
#pragma unroll
    for (int nt = 0; nt < 4; ++nt) {
        bf8_t bfr = *(const bf8_t*)(qabs + (size_t)h * 2048 + (nt * 16 + tl) * 32 + qd * 8);
        C3[nt] = __builtin_amdgcn_mfma_f32_16x16x32_bf16(an, bfr, C3[nt], 0, 0, 0);
    }
#pragma unroll
    for (int nt = 0; nt < 4; ++nt)
#pragma unroll
        for (int r = 0; r < 4; ++r)
            qf[(qd * 4 + r) * 136 + nt * 16 + tl] = f2bf(C3[nt][r]);
#pragma unroll
    for (int nt2 = 0; nt2 < 4; ++nt2) {
        int p = (nt2 * 16 + tl) >> 1;
        int outc = evn ? (64 + p) : (96 + p);
#pragma unroll
        for (int r = 0; r < 4; ++r) {
            float val = C2[nt2 + 2][r];
            float part = __shfl_xor(val, 1);
            float res = evn ? (val * csv[nt2][r] - part * snv[nt2][r])
                            : (val * csv[nt2][r] + part * snv[nt2][r]);
            qf[(qd * 4 + r) * 136 + outc] = f2bf(res);
        }
    }
    size_t qb = ((size_t)(bb * 8 + h) * 2048 + pos0) * 128;
#pragma unroll
    for (int i = 0; i < 4; ++i) {
        int idx = i * 64 + lane;
        int row = idx >> 4, c = idx & 15;
        uint4 v = *(const uint4*)(qf + row * 136 + c * 8);
        *(uint4*)(Qbf + qb + (size_t)row * 128 + c * 8) = v;
    }
}

// ---------------------------------------------------------------------------
// k3 v10: wave owns 64 q (groups A-D), block = 4 waves = 256 q. grid
// (8,8,4) = 256 blocks = 1 block/CU. Each K/V-fragment read feeds 4 MFMAs;
// staging per CU halves. Strides 136/72 (proven), 2 barriers/tile, NO-SHIFT
// exp2 softmax, cvt_pk P-pack, setprio. LDS: Kt 8704 + Vt 4608 + Pw
// 4*64*72 = 31744 shorts = 63488 B.
// ---------------------------------------------------------------------------
__global__ __launch_bounds__(256, 1) void k3_attn(
    const ushort_t* __restrict__ Qbf, const ushort_t* __restrict__ Kbf,
    const ushort_t* __restrict__ VTbf, const float* __restrict__ oaT,
    ushort_t* __restrict__ ctxb)
{
    __shared__ __align__(16) ushort_t LDS[31744];
    ushort_t* Kt = LDS;                    // [64][136]
    ushort_t* Vt = LDS + 8704;             // [64][72]
    ushort_t* Pw = LDS + 13312;            // [4][64][72]
    int j = threadIdx.x;
    int b = blockIdx.z, h = blockIdx.y, q0g = blockIdx.x * 256;
    int w = j >> 6, lane = j & 63;
    int tl = lane & 15, qd = lane >> 4;
    ushort_t* Pme = Pw + w * 4608;
    int qw = q0g + w * 64;

    bf8_t qf[4][4];   // [group][ks]
    {
        const ushort_t* qp = Qbf + ((size_t)((b * 8 + h) * 2048) + qw + tl) * 128 + qd * 8;
#pragma unroll
        for (int g = 0; g < 4; ++g)
#pragma unroll
            for (int ks = 0; ks < 4; ++ks)
                qf[g][ks] = *(const bf8_t*)(qp + (size_t)(g * 16) * 128 + ks * 32);
    }
    f4_t Oacc[4][4];  // [group][nt]
#pragma unroll
    for (int g = 0; g < 4; ++g)
#pragma unroll
        for (int nt = 0; nt < 4; ++nt)
            Oacc[g][nt] = (f4_t){0.f, 0.f, 0.f, 0.f};
    float lsum[4] = {0.f, 0.f, 0.f, 0.f};

    const size_t kbase = (size_t)b * 2048 * 128;
    const size_t vbase = (size_t)b * 64 * 2048;

    for (int it = 0; it < 32; ++it) {
        __syncthreads();
        {   // stage Kt: 256 thr x 32 shorts (4 x uint4)
            int r = j >> 2, c0 = (j & 3) * 32;
            const uint4* gp = (const uint4*)(Kbf + kbase + (size_t)(it * 64 + r) * 128 + c0);
            uint4 a0 = gp[0], a1 = gp[1], a2 = gp[2], a3 = gp[3];
            uint4* dp = (uint4*)(Kt + r * 136 + c0);
            dp[0] = a0; dp[1] = a1; dp[2] = a2; dp[3] = a3;
        }
        {   // stage Vt: 256 thr x 16 shorts (2 x uint4)
            int d = j >> 2, c0 = (j & 3) * 16;
            const uint4* gp = (const uint4*)(VTbf + vbase + (size_t)d * 2048 + it * 64 + c0);
            uint4 a0 = gp[0], a1 = gp[1];
            uint4* dp = (uint4*)(Vt + d * 72 + c0);
            dp[0] = a0; dp[1] = a1;
        }
        __syncthreads();
        // scores S^T for 4 groups; K-fragment shared across groups
        f4_t S[4][4];  // [group][nt]
        __builtin_amdgcn_s_setprio(1);
#pragma unroll
        for (int nt = 0; nt < 4; ++nt) {
            bf8_t kf[4];
#pragma unroll
            for (int ks = 0; ks < 4; ++ks)
                kf[ks] = *(const bf8_t*)(Kt + (nt * 16 + tl) * 136 + ks * 32 + qd * 8);
            f4_t c0 = (f4_t){0.f, 0.f, 0.f, 0.f};
            f4_t c1 = (f4_t){0.f, 0.f, 0.f, 0.f};
            f4_t c2 = (f4_t){0.f, 0.f, 0.f, 0.f};
            f4_t c3 = (f4_t){0.f, 0.f, 0.f, 0.f};
#pragma unroll
            for (int ks = 0; ks < 4; ++ks) {
                c0 = __builtin_amdgcn_mfma_f32_16x16x32_bf16(kf[ks], qf[0][ks], c0, 0, 0, 0);
                c1 = __builtin_amdgcn_mfma_f32_16x16x32_bf16(kf[ks], qf[1][ks], c1, 0, 0, 0);
                c2 = __builtin_amdgcn_mfma_f32_16x16x32_bf16(kf[ks], qf[2][ks], c2, 0, 0, 0);
                c3 = __builtin_amdgcn_mfma_f32_16x16x32_bf16(kf[ks], qf[3][ks], c3, 0, 0, 0);
            }
            S[0][nt] = c0; S[1][nt] = c1; S[2][nt] = c2; S[3][nt] = c3;
        }
        __builtin_amdgcn_s_setprio(0);
        // no-shift softmax: P = exp2(S); l += sum; P -> LDS via cvt_pk
#pragma unroll
        for (int g = 0; g < 4; ++g) {
            float rs = 0.f;
#pragma unroll
            for (int nt = 0; nt < 4; ++nt)
#pragma unroll
                for (int r = 0; r < 4; ++r) {
                    float p = fexp2(S[g][nt][r]); S[g][nt][r] = p; rs += p;
                }
            rs += __shfl_xor(rs, 16); rs += __shfl_xor(rs, 32);
            lsum[g] += rs;
#pragma unroll
            for (int nt = 0; nt < 4; ++nt) {
                uint2 pk;
                pk.x = cvtpk_bf16(S[g][nt][0], S[g][nt][1]);
                pk.y = cvtpk_bf16(S[g][nt][2], S[g][nt][3]);
                *(uint2*)(Pme + (g * 16 + tl) * 72 + nt * 16 + qd * 4) = pk;
            }
        }
        // PV: V-fragment shared across groups
        bf8_t pf[4][2];
#pragma unroll
        for (int g = 0; g < 4; ++g)
#pragma unroll
            for (int ks = 0; ks < 2; ++ks)
                pf[g][ks] = *(const bf8_t*)(Pme + (g * 16 + tl) * 72 + ks * 32 + qd * 8);
        __builtin_amdgcn_s_setprio(1);
#pragma unroll
        for (int nt = 0; nt < 4; ++nt) {
            bf8_t vf[2];
#pragma unroll
            for (int ks = 0; ks < 2; ++ks)
                vf[ks] = *(const bf8_t*)(Vt + (nt * 16 + tl) * 72 + ks * 32 + qd * 8);
#pragma unroll
            for (int ks = 0; ks < 2; ++ks) {
                Oacc[0][nt] = __builtin_amdgcn_mfma_f32_16x16x32_bf16(pf[0][ks], vf[ks], Oacc[0][nt], 0, 0, 0);
                Oacc[1][nt] = __builtin_amdgcn_mfma_f32_16x16x32_bf16(pf[1][ks], vf[ks], Oacc[1][nt], 0, 0, 0);
                Oacc[2][nt] = __builtin_amdgcn_mfma_f32_16x16x32_bf16(pf[2][ks], vf[ks], Oacc[2][nt], 0, 0, 0);
                Oacc[3][nt] = __builtin_amdgcn_mfma_f32_16x16x32_bf16(pf[3][ks], vf[ks], Oacc[3][nt], 0, 0, 0);
            }
        }
        __builtin_amdgcn_s_setprio(0);
    }
    // normalize O into Pme rows (64 q rows per wave)
    {
#pragma unroll
        for (int g = 0; g < 4; ++g) {
            float linv[4];
#pragma unroll
            for (int r = 0; r < 4; ++r) {
                float lq = __shfl(lsum[g], (lane & 48) + qd * 4 + r);
                linv[r] = 1.f / lq;
            }
#pragma unroll
            for (int nt = 0; nt < 4; ++nt)
#pragma unroll
                for (int r = 0; r < 4; ++r)
                    Pme[(g * 16 + qd * 4 + r) * 72 + nt * 16 + tl] = f2bf(Oacc[g][nt][r] * linv[r]);
        }
    }
    __syncthreads();
    ushort_t* OA = LDS;  // [96][72] = 6912 sh, fits in Kt region
    for (int e = j; e < 96 * 64; e += 256) {
        int v = e >> 6, r = e & 63;
        OA[v * 72 + r] = f2bf(oaT[h * 6144 + r * 96 + v]);
    }
    __syncthreads();
    {   // ctx[q][v] = sum_r O[q][r] * oa[r][v], per group
#pragma unroll
        for (int g = 0; g < 4; ++g) {
            bf8_t of[2];
#pragma unroll
            for (int ks = 0; ks < 2; ++ks)
                of[ks] = *(const bf8_t*)(Pme + (g * 16 + tl) * 72 + ks * 32 + qd * 8);
            __builtin_amdgcn_s_setprio(1);
#pragma unroll
            for (int nt = 0; nt < 6; ++nt) {
                f4_t c = (f4_t){0.f, 0.f, 0.f, 0.f};
#pragma unroll
                for (int ks = 0; ks < 2; ++ks) {
                    bf8_t af = *(const bf8_t*)(OA + (nt * 16 + tl) * 72 + ks * 32 + qd * 8);
                    c = __builtin_amdgcn_mfma_f32_16x16x32_bf16(of[ks], af, c, 0, 0, 0);
                }
#pragma unroll
                for (int r = 0; r < 4; ++r) {
                    size_t tok = (size_t)(b * 2048 + qw + g * 16 + qd * 4 + r);
                    ctxb[tok * 768 + h * 96 + nt * 16 + tl] = f2bf(c[r]);
                }
            }
            __builtin_amdgcn_s_setprio(0);
        }
    }
}

// ---------------------------------------------------------------------------
// k5a v2: LDS-tiled GEMM y = ctx @ wo^T + src -> ybf.
// ---------------------------------------------------------------------------
__global__ __launch_bounds__(512, 2) void k5a_gemm(
    const void* __restrict__ src, const void* __restrict__ nw,
    const float* __restrict__ ws,
    const ushort_t* __restrict__ ctxb, ushort_t* __restrict__ ybf)
{
    const ushort_t* woB = (const ushort_t*)(ws + OFF_WOT);
    const int isbf = get_isbf(nw);
    __shared__ __align__(16) ushort_t sB[384 * 72];   // 55296 B
    __shared__ __align__(16) ushort_t sA[32 * 72];    //  4608 B
    int j = threadIdx.x;
    int bx = blockIdx.x;
    int t0 = (bx >> 1) * 32;
    int colh = (bx & 1) * 384;
    int w = j >> 6, lane = j & 63;
    int tl = lane & 15, qd = lane >> 4;
    int mt = w & 1;
    int n0l = (w >> 1) * 96;          // wave's col offset within the 384

    f4_t acc[6];
#pragma unroll
    for (int nt = 0; nt < 6; ++nt) acc[nt] = (f4_t){0.f, 0.f, 0.f, 0.f};

    for (int kb = 0; kb < 12; ++kb) {
        __syncthreads();
        {   // stage B: wo rows colh..colh+383, cols kb*64..+63 (8 x uint4/row)
            for (int e = j; e < 384 * 8; e += 512) {
                int rr = e >> 3, ch = e & 7;
                uint4 v = *(const uint4*)(woB + (size_t)(colh + rr) * 768 + kb * 64 + ch * 8);
                *(uint4*)(sB + rr * 72 + ch * 8) = v;
            }
        }
        if (j < 256) {  // stage A: ctx rows t0..t0+31, cols kb*64..+63
            int rr = j >> 3, ch = j & 7;
            uint4 v = *(const uint4*)(ctxb + (size_t)(t0 + rr) * 768 + kb * 64 + ch * 8);
            *(uint4*)(sA + rr * 72 + ch * 8) = v;
        }
        __syncthreads();
        __builtin_amdgcn_s_setprio(1);
#pragma unroll
        for (int ks = 0; ks < 2; ++ks) {
            bf8_t a = *(const bf8_t*)(sA + (mt * 16 + tl) * 72 + ks * 32 + qd * 8);
#pragma unroll
            for (int nt = 0; nt < 6; ++nt) {
                bf8_t bfr = *(const bf8_t*)(sB + (n0l + nt * 16 + tl) * 72 + ks * 32 + qd * 8);
                acc[nt] = __builtin_amdgcn_mfma_f32_16x16x32_bf16(a, bfr, acc[nt], 0, 0, 0);
            }
        }
        __builtin_amdgcn_s_setprio(0);
    }
    // epilogue: residual add, store y bf16
#pragma unroll
    for (int nt = 0; nt < 6; ++nt)
#pragma unroll
        for (int r = 0; r < 4; ++r) {
            int row = t0 + mt * 16 + qd * 4 + r;
            int col = colh + n0l + nt * 16 + tl;
            float yv = acc[nt][r] + ldin(src, (size_t)row * 768 + col, isbf);
            ybf[(size_t)row * 768 + col] = f2bf(yv);
        }
}

// ---------------------------------------------------------------------------
// k5b: streaming RMSNorm y -> out. 16 tokens/block, grid 512, 256 thr.
// ---------------------------------------------------------------------------
__global__ __launch_bounds__(256) void k5b_norm(
    const void* __restrict__ nw_in, const float* __restrict__ ws,
    const ushort_t* __restrict__ ybf, void* __restrict__ out)
{
    const float* nw = ws + OFF_NW;
    const int isbf = get_isbf(nw_in);
    int j = threadIdx.x;
    int tt = j >> 4, s = j & 15;
    size_t row = (size_t)blockIdx.x * 16 + tt;
    const ushort_t* yp = ybf + row * 768 + s * 48;

    float val[48];
    float ss = 0.f;
#pragma unroll
    for (int c8 = 0; c8 < 6; ++c8) {
        union { uint4 u; ushort_t h[8]; } uu;
        uu.u = ((const uint4*)yp)[c8];
#pragma unroll
        for (int c = 0; c < 8; ++c) {
            float v = bf2f(uu.h[c]);
            val[c8 * 8 + c] = v;
            ss += v * v;
        }
    }
    ss += __shfl_xor(ss, 1); ss += __shfl_xor(ss, 2);
    ss += __shfl_xor(ss, 4); ss += __shfl_xor(ss, 8);
    float rs = rsqrtf(ss * (1.f / 768.f) + EPSF);
    const float* nwp = nw + s * 48;
    size_t base = row * 768 + s * 48;
    if (isbf) {
        ushort_t* op = (ushort_t*)out + base;
#pragma unroll
        for (int c8 = 0; c8 < 6; ++c8) {
            union { uint4 u; ushort_t h[8]; } uu;
#pragma unroll
            for (int c = 0; c < 8; ++c) {
                float hv = bf2f(f2bf(val[c8 * 8 + c] * rs));
                uu.h[c] = f2bf(hv * nwp[c8 * 8 + c]);
            }
            ((uint4*)op)[c8] = uu.u;
        }
    } else {
        float* op = (float*)out + base;
#pragma unroll
        for (int c4 = 0; c4 < 12; ++c4) {
            float4 f;
            f.x = val[c4 * 4 + 0] * rs * nwp[c4 * 4 + 0];
            f.y = val[c4 * 4 + 1] * rs * nwp[c4 * 4 + 1];
            f.z = val[c4 * 4 + 2] * rs * nwp[c4 * 4 + 2];
            f.w = val[c4 * 4 + 3] * rs * nwp[c4 * 4 + 3];
            ((float4*)op)[c4] = f;
        }
    }
}

// ---------------------------------------------------------------------------
extern "C" void kernel_launch(void* const* d_in, const int* in_sizes, int n_in,
                              void* d_out, int out_size, void* d_ws, size_t ws_size,
                              hipStream_t stream)
{
    const void* src   = d_in[0];
    const void* wq_a  = d_in[1];
    const void* q_ln  = d_in[2];
    const void* wq_b  = d_in[3];
    const void* wkv_a = d_in[4];
    const void* kv_ln = d_in[5];
    const void* wkv_b = d_in[6];
    const void* wo    = d_in[7];
    const void* nw    = d_in[8];
    float* ws = (float*)d_ws;
    ushort_t* Kbf   = (ushort_t*)(ws + OFF_KBF);
    ushort_t* VTbf  = (ushort_t*)(ws + OFF_VTB);
    ushort_t* Qbf   = (ushort_t*)(ws + OFF_QBF);
    ushort_t* ctxb  = (ushort_t*)(ws + OFF_CTXF);
    ushort_t* ybf   = Qbf;   // Q' dead after k3; reuse as y [8192][768]
    ushort_t* qn    = ctxb;  // ctx region dead until k3; reuse as qn [8192][64]

    prep_k<<<dim3(PB7), dim3(256), 0, stream>>>(wq_a, q_ln, wq_b, wkv_a, kv_ln, wkv_b, wo, nw, ws);
    k1_ckv<<<dim3(TOK / 32), dim3(512), 0, stream>>>(src, nw, ws, Kbf, VTbf, qn);
    k2b_q<<<dim3(TOK / 32 * 2), dim3(512), 0, stream>>>(ws, qn, Qbf);
    k3_attn<<<dim3(8, 8, 4), dim3(256), 0, stream>>>(Qbf, Kbf, VTbf, ws + OFF_OAT, ctxb);
    k5a_gemm<<<dim3(TOK / 32 * 2), dim3(512), 0, stream>>>(src, nw, ws, ctxb, ybf);
    k5b_norm<<<dim3(TOK / 16), dim3(256), 0, stream>>>(nw, ws, ybf, d_out);
}

// Round 15
// 252.254 us; speedup vs baseline: 1.0315x; 1.0315x over previous
//
#include <hip/hip_runtime.h>

// ---------------------------------------------------------------------------
// MLA prefill (B=4, S=2048, D=768, H=8, q_rank=kv_rank=rope=64, nope=32, v=96)
// Round 24:
//  - k3 reverted to v7.1 EXACT (round-22: 89.5us; v10 64q/wave refuted:
//    96.4us at 1 wave/SIMD, pre-registered failure mode).
//  - k1 v4: ckv GEMM B-panel (wkv_a) now LDS-staged per K-step of 64
//    (k5a recipe, 3x proven) replacing 24 dependent global B-loads/wave.
//    LDS 85KB (sA 49.7K + sB 18.4K + ckv 16.9K), 1 block/CU as before.
// k2b/k5a/k5b/prep = round-22 exact (248.2us verified).
// ---------------------------------------------------------------------------

#define DEV static __device__ __forceinline__
typedef unsigned short ushort_t;
typedef __attribute__((ext_vector_type(8))) short bf8_t;
typedef __attribute__((ext_vector_type(4))) float f4_t;

DEV float bf2f(unsigned int u) {
    union { float f; unsigned int i; } x; x.i = u << 16; return x.f;
}
DEV ushort_t f2bf(float f) {
    union { float f; unsigned int u; } x; x.f = f;
    unsigned int u = x.u;
    return (ushort_t)((u + 0x7fffu + ((u >> 16) & 1u)) >> 16);
}
DEV unsigned cvtpk_bf16(float lo, float hi) {   // packed f32x2 -> bf16x2, RNE
    unsigned r;
    asm("v_cvt_pk_bf16_f32 %0, %1, %2" : "=v"(r) : "v"(lo), "v"(hi));
    return r;
}
DEV float ldin(const void* p, size_t i, int isbf) {
    return isbf ? bf2f(((const ushort_t*)p)[i]) : ((const float*)p)[i];
}
DEV float fexp2(float x) {
#if __has_builtin(__builtin_amdgcn_exp2f)
    return __builtin_amdgcn_exp2f(x);
#else
    return exp2f(x);
#endif
}
DEV int get_isbf(const void* nw) {
    return ((((const unsigned int*)nw)[0] & 0xffffu) != 0u) ? 1 : 0;
}

constexpr int   TOK   = 4 * 2048;                         // 8192 tokens
constexpr float EPSF  = 1e-6f;
// Q' carries SCALE*log2(e) so softmax uses native exp2
constexpr float QSCALE = (float)(0.10206207261596575 * 1.4426950408889634);
constexpr float L2_10000_OVER_32 = 0.4152410118609203f;   // log2(10000)/32

// workspace layout (float offsets)
constexpr size_t OFF_WOT   = 0;                 // wo bf16 [768][768]
constexpr size_t OFF_WKVAT = 589824;            // wkv_a bf16 [128][768] (k1 B)
constexpr size_t OFF_WQAT  = 688128;            // wq_a bf16 [64][768] (k1 qn B)
constexpr size_t OFF_WQBT  = 737280;            // wq_b bf16 [768][64] (k2b B)
constexpr size_t OFF_QAF   = 786432;            // q_absorbT*QSCALE bf16 [8][64][32]
constexpr size_t OFF_OAT   = 802816;            // out_absorbT [8][64][96] fp32
constexpr size_t OFF_QLN   = 851968;
constexpr size_t OFF_KVLN  = 852032;
constexpr size_t OFF_NW    = 852096;
constexpr size_t OFF_FLAG  = 852864;            // (unused since round 12)
constexpr size_t OFF_CTXF  = 852880;            // ctx bf16 [8192][768]; qn bf16 [8192][64] before k3
constexpr size_t OFF_SRCBF = 3998608;           // (dead since round 21)
constexpr size_t OFF_KBF   = 7144336;           // K' bf16 [4][2048][128]
constexpr size_t OFF_VTB   = 7668624;           // V^T bf16 [4][64][2048]
constexpr size_t OFF_QBF   = 7930768;           // Q' bf16 [4][8][2048][128]; y bf16 [8192][768] after k3
constexpr size_t OFF_ROPE  = 12125072;          // rope table float2 [2048][32]

// prep 1D-grid segment offsets (256-thr blocks)
constexpr int PB0 = 2304;            // wo copy        [0, 2304)
constexpr int PB1 = PB0 + 384;       // wkv_a          [2304, 2688)
constexpr int PB2 = PB1 + 192;       // wq_a           [2688, 2880)
constexpr int PB3 = PB2 + 192;       // wq_b           [2880, 3072)
constexpr int PB4 = PB3 + 64;        // q_absorbT      [3072, 3136)
constexpr int PB5 = PB4 + 192;       // out_absorbT    [3136, 3328)
constexpr int PB6 = PB5 + 4;         // norm vectors   [3328, 3332)
constexpr int PB7 = PB6 + 256;       // rope table     [3332, 3588)

// ---------------------------------------------------------------------------
__global__ __launch_bounds__(256) void prep_k(
    const void* __restrict__ wq_a, const void* __restrict__ q_ln,
    const void* __restrict__ wq_b, const void* __restrict__ wkv_a,
    const void* __restrict__ kv_ln, const void* __restrict__ wkv_b,
    const void* __restrict__ wo, const void* __restrict__ nw,
    float* __restrict__ ws)
{
    const int isbf = get_isbf(nw);
    const int bid = blockIdx.x;
    const int tid = threadIdx.x;
    if (bid < PB0) {        // wo -> bf16 straight copy
        int i = bid * 256 + tid;
        ushort_t* wob = (ushort_t*)(ws + OFF_WOT);
        wob[i] = isbf ? ((const ushort_t*)wo)[i] : f2bf(((const float*)wo)[i]);
    } else if (bid < PB1) { // wkv_a bf16 straight [128][768]
        int i = (bid - PB0) * 256 + tid;
        ushort_t* d = (ushort_t*)(ws + OFF_WKVAT);
        d[i] = isbf ? ((const ushort_t*)wkv_a)[i] : f2bf(((const float*)wkv_a)[i]);
    } else if (bid < PB2) { // wq_a bf16 straight [64][768]
        int i = (bid - PB1) * 256 + tid;
        ushort_t* d = (ushort_t*)(ws + OFF_WQAT);
        d[i] = isbf ? ((const ushort_t*)wq_a)[i] : f2bf(((const float*)wq_a)[i]);
    } else if (bid < PB3) { // wq_b bf16 straight [768][64]
        int i = (bid - PB2) * 256 + tid;
        ushort_t* d = (ushort_t*)(ws + OFF_WQBT);
        d[i] = isbf ? ((const ushort_t*)wq_b)[i] : f2bf(((const float*)wq_b)[i]);
    } else if (bid < PB4) { // q_absorbT * QSCALE bf16 [8][r=64][d=32]
        int i = (bid - PB3) * 256 + tid;
        int h = i >> 11, rem = i & 2047, r = rem >> 5, d = rem & 31;
        ushort_t* dst = (ushort_t*)(ws + OFF_QAF);
        dst[i] = f2bf(ldin(wkv_b, (size_t)(h * 128 + d) * 64 + r, isbf) * QSCALE);
    } else if (bid < PB5) { // out_absorbT [h][r][v] fp32
        int i = (bid - PB4) * 256 + tid;
        int h = i / 6144, rem = i - h * 6144;
        int r = rem / 96, v = rem - r * 96;
        ws[OFF_OAT + i] = ldin(wkv_b, (size_t)h * 8192 + 2048 + v * 64 + r, isbf);
    } else if (bid < PB6) { // norm vectors (896 elements)
        int i = (bid - PB5) * 256 + tid;
        if (i < 64)             ws[OFF_QLN + i]       = ldin(q_ln, i, isbf);
        else if (i < 128)       ws[OFF_KVLN + i - 64] = ldin(kv_ln, i - 64, isbf);
        else if (i < 128 + 768) ws[OFF_NW + i - 128]  = ldin(nw, i - 128, isbf);
    } else {                // rope table [pos][p] = (cos, sin)
        int i = (bid - PB6) * 256 + tid;
        int pos = i >> 5, p = i & 31;
        float inv = exp2f(-(float)p * L2_10000_OVER_32);
        float ang = (float)pos * inv;
        float2* tab = (float2*)(ws + OFF_ROPE);
        tab[i] = make_float2(cosf(ang), sinf(ang));
    }
}

// ---------------------------------------------------------------------------
// k1 v4: ckv GEMM with B staged per K-step of 64 (k5a recipe) + epilogue +
// merged qn pass (waves 0-1, from sA). LDS: sA 49664 + sB 18432 + ckv 16896.
// ---------------------------------------------------------------------------
__global__ __launch_bounds__(512) void k1_ckv(
    const void* __restrict__ src, const void* __restrict__ nw,
    const float* __restrict__ ws,
    ushort_t* __restrict__ Kbf, ushort_t* __restrict__ VTbf,
    ushort_t* __restrict__ qn_all)
{
    const ushort_t* wkvab = (const ushort_t*)(ws + OFF_WKVAT);  // [128][768]
    const ushort_t* wqab  = (const ushort_t*)(ws + OFF_WQAT);   // [64][768]
    const float* kvln  = ws + OFF_KVLN;
    const float* qln   = ws + OFF_QLN;
    const float2* tab  = (const float2*)(ws + OFF_ROPE);
    const int isbf = get_isbf(nw);
    __shared__ __align__(16) ushort_t sA[32 * 776];
    __shared__ __align__(16) ushort_t sB[128 * 72];
    __shared__ __align__(16) float ckv[32][132];
    int j = threadIdx.x;
    int t0 = blockIdx.x * 32;
    int w = j >> 6, lane = j & 63;
    int tl = lane & 15, qd = lane >> 4;

    {   // stage A: src[t0..t0+31][0..767] -> sA bf16 (stride 776)
        for (int e = j; e < 32 * 96; e += 512) {
            int row = e / 96, c8 = e - row * 96;
            size_t off = (size_t)(t0 + row) * 768 + c8 * 8;
            if (isbf) {
                uint4 v = *(const uint4*)((const ushort_t*)src + off);
                *(uint4*)(sA + row * 776 + c8 * 8) = v;
            } else {
                const float4* p = (const float4*)((const float*)src + off);
                float4 f0 = p[0], f1 = p[1];
                ushort_t tmp[8] = {f2bf(f0.x), f2bf(f0.y), f2bf(f0.z), f2bf(f0.w),
                                   f2bf(f1.x), f2bf(f1.y), f2bf(f1.z), f2bf(f1.w)};
                uint4 v = *(const uint4*)tmp;
                *(uint4*)(sA + row * 776 + c8 * 8) = v;
            }
        }
    }
    __syncthreads();
    {   // GEMM: ckv[32][128] = A @ wkv_a^T; B[128][64] staged per K-step
        f4_t acc[2];
        acc[0] = (f4_t){0.f, 0.f, 0.f, 0.f};
        acc[1] = (f4_t){0.f, 0.f, 0.f, 0.f};
        for (int kb = 0; kb < 12; ++kb) {
            __syncthreads();
            // stage sB: wkv_a rows 0..127, cols kb*64..+63 (1024 uint4, 2/thr)
            for (int e = j; e < 1024; e += 512) {
                int rr = e >> 3, ch = e & 7;
                uint4 v = *(const uint4*)(wkvab + (size_t)rr * 768 + kb * 64 + ch * 8);
                *(uint4*)(sB + rr * 72 + ch * 8) = v;
            }
            __syncthreads();
            const ushort_t* bp = sB + (w * 16 + tl) * 72 + qd * 8;
            const ushort_t* ap = sA + tl * 776 + kb * 64 + qd * 8;
#pragma unroll
            for (int ks = 0; ks < 2; ++ks) {
                bf8_t b  = *(const bf8_t*)(bp + ks * 32);
                bf8_t a0 = *(const bf8_t*)(ap + ks * 32);
                bf8_t a1 = *(const bf8_t*)(ap + 16 * 776 + ks * 32);
                acc[0] = __builtin_amdgcn_mfma_f32_16x16x32_bf16(a0, b, acc[0], 0, 0, 0);
                acc[1] = __builtin_amdgcn_mfma_f32_16x16x32_bf16(a1, b, acc[1], 0, 0, 0);
            }
        }
#pragma unroll
        for (int mt = 0; mt < 2; ++mt)
#pragma unroll
            for (int r = 0; r < 4; ++r)
                ckv[mt * 16 + qd * 4 + r][w * 16 + tl] = acc[mt][r];
    }
    __syncthreads();

    if (j < 256) {
        int tt = j >> 3, l = j & 7;
        float ss = 0.f;
#pragma unroll
        for (int i = 0; i < 8; ++i) { float v = ckv[tt][l * 8 + i]; ss += v * v; }
        ss += __shfl_xor(ss, 1); ss += __shfl_xor(ss, 2); ss += __shfl_xor(ss, 4);
        float rs = rsqrtf(ss * (1.f / 64.f) + EPSF);
        size_t base = (size_t)(t0 + tt) * 128;
        ushort_t kb[8];
        float clw[8];
#pragma unroll
        for (int i = 0; i < 8; ++i) {
            int o2 = l * 8 + i;
            float cl = ckv[tt][o2] * rs;
            if (isbf) cl = bf2f(f2bf(cl));   // reference: .astype(bf16) before *w
            clw[i] = cl * kvln[o2];
            kb[i] = f2bf(clw[i]);
        }
        uint4 pack;
        pack.x = kb[0] | ((unsigned)kb[1] << 16); pack.y = kb[2] | ((unsigned)kb[3] << 16);
        pack.z = kb[4] | ((unsigned)kb[5] << 16); pack.w = kb[6] | ((unsigned)kb[7] << 16);
        *(uint4*)&Kbf[base + l * 8] = pack;
        int pos = (t0 + tt) & 2047;
        ushort_t r0[4], r1[4];
#pragma unroll
        for (int i = 0; i < 4; ++i) {
            int p = l * 4 + i;
            float2 cssn = tab[pos * 32 + p];
            float e = ckv[tt][64 + 2 * p], od = ckv[tt][64 + 2 * p + 1];
            r0[i] = f2bf(e * cssn.x - od * cssn.y);
            r1[i] = f2bf(od * cssn.x + e * cssn.y);
        }
        uint2 p0, p1;
        p0.x = r0[0] | ((unsigned)r0[1] << 16); p0.y = r0[2] | ((unsigned)r0[3] << 16);
        p1.x = r1[0] | ((unsigned)r1[1] << 16); p1.y = r1[2] | ((unsigned)r1[3] << 16);
        *(uint2*)&Kbf[base + 64 + l * 4] = p0;
        *(uint2*)&Kbf[base + 96 + l * 4] = p1;
#pragma unroll
        for (int i = 0; i < 8; ++i) ckv[tt][l * 8 + i] = clw[i];
    }
    __syncthreads();
    if (j < 256) {   // VT[b][r][t] = c_lat_n[t][r]
        int t = j & 31, rb = (j >> 5) * 8;
        int bb = t0 >> 11, col = (t0 & 2047) + t;
#pragma unroll
        for (int i = 0; i < 8; ++i) {
            int r = rb + i;
            VTbf[((size_t)(bb * 64 + r)) * 2048 + col] = f2bf(ckv[t][r]);
        }
    }
    __syncthreads();   // ckv free for reuse as qn bounce
    if (w < 2) {       // merged qn pass: wave w -> tokens t0 + w*16 .. +15
        f4_t C1[4];
#pragma unroll
        for (int nt = 0; nt < 4; ++nt) C1[nt] = (f4_t){0.f, 0.f, 0.f, 0.f};
        const ushort_t* ap = sA + (size_t)(w * 16 + tl) * 776 + qd * 8;
#pragma unroll 4
        for (int ks = 0; ks < 24; ++ks) {
            bf8_t a = *(const bf8_t*)(ap + ks * 32);
#pragma unroll
            for (int nt = 0; nt < 4; ++nt) {
                bf8_t bfr = *(const bf8_t*)(wqab + (size_t)(nt * 16 + tl) * 768 + ks * 32 + qd * 8);
                C1[nt] = __builtin_amdgcn_mfma_f32_16x16x32_bf16(a, bfr, C1[nt], 0, 0, 0);
            }
        }
        float rsv[4];
#pragma unroll
        for (int r = 0; r < 4; ++r) {
            float s = C1[0][r] * C1[0][r] + C1[1][r] * C1[1][r]
                    + C1[2][r] * C1[2][r] + C1[3][r] * C1[3][r];
            s += __shfl_xor(s, 1); s += __shfl_xor(s, 2);
            s += __shfl_xor(s, 4); s += __shfl_xor(s, 8);
            rsv[r] = rsqrtf(s * (1.f / 64.f) + EPSF);
        }
        float qlnv[4];
#pragma unroll
        for (int nt = 0; nt < 4; ++nt) qlnv[nt] = qln[nt * 16 + tl];
        ushort_t* tmpn = (ushort_t*)&ckv[0][0] + w * 1152;
#pragma unroll
        for (int nt = 0; nt < 4; ++nt)
#pragma unroll
            for (int r = 0; r < 4; ++r) {
                float v = C1[nt][r] * rsv[r];
                if (isbf) v = bf2f(f2bf(v));  // .astype(bf16) before *w
                tmpn[(qd * 4 + r) * 72 + nt * 16 + tl] = f2bf(v * qlnv[nt]);
            }
#pragma unroll
        for (int i = 0; i < 2; ++i) {
            int e = i * 64 + lane;
            int row = e >> 3, ch = e & 7;
            uint4 v = *(const uint4*)(tmpn + row * 72 + ch * 8);
            *(uint4*)(qn_all + (size_t)(t0 + w * 16 + row) * 64 + ch * 8) = v;
        }
    }
}

// ---------------------------------------------------------------------------
// k2b: Q' = rope/absorb(qn @ wq_b^T). Block = 32 tok x 384 cols (4 heads),
// 512 thr (8 waves); wave = 16 tok x 1 head. wq_b staged once in LDS.
// ---------------------------------------------------------------------------
__global__ __launch_bounds__(512) void k2b_q(
    const float* __restrict__ ws, const ushort_t* __restrict__ qn_all,
    ushort_t* __restrict__ Qbf)
{
    const ushort_t* wqbb = (const ushort_t*)(ws + OFF_WQBT);   // [768][64]
    const ushort_t* qabs = (const ushort_t*)(ws + OFF_QAF);    // [8][64][32] *QSCALE
    const float2*   tab  = (const float2*)(ws + OFF_ROPE);

    __shared__ __align__(16) ushort_t sB[384 * 72];    // 27648 sh
    __shared__ __align__(16) ushort_t sA[32 * 72];     //  2304 sh
    __shared__ __align__(16) ushort_t PW[8 * 2816];    // per wave: qn 640 + qf 2176
    int j = threadIdx.x;
    int bx = blockIdx.x;
    int t0 = (bx >> 1) * 32;
    int colh = (bx & 1) * 384;
    int w = j >> 6, lane = j & 63;
    int tl = lane & 15, qd = lane >> 4;
    int mt = w & 1, hh = w >> 1;
    int h = (bx & 1) * 4 + hh;
    ushort_t* qnb = PW + w * 2816;
    ushort_t* qf  = qnb + 640;
    int tokw = t0 + mt * 16;

    {   // stage B: wq_b rows colh..colh+383 x 64 k (384 x 8 uint4)
        for (int e = j; e < 384 * 8; e += 512) {
            int rr = e >> 3, ch = e & 7;
            uint4 v = *(const uint4*)(wqbb + (size_t)(colh + rr) * 64 + ch * 8);
            *(uint4*)(sB + rr * 72 + ch * 8) = v;
        }
    }
    if (j < 256) {  // stage A: qn rows t0..t0+31 x 64
        int rr = j >> 3, ch = j & 7;
        uint4 v = *(const uint4*)(qn_all + (size_t)(t0 + rr) * 64 + ch * 8);
        *(uint4*)(sA + rr * 72 + ch * 8) = v;
    }
    __syncthreads();

    bf8_t A2[2];
#pragma unroll
    for (int ks = 0; ks < 2; ++ks)
        A2[ks] = *(const bf8_t*)(sA + (mt * 16 + tl) * 72 + ks * 32 + qd * 8);

    // rope cos/sin preload, scaled by QSCALE
    float csv[4][4], snv[4][4];
#pragma unroll
    for (int nt2 = 0; nt2 < 4; ++nt2) {
        int p = (nt2 * 16 + tl) >> 1;
#pragma unroll
        for (int r = 0; r < 4; ++r) {
            int pos = (tokw + qd * 4 + r) & 2047;
            float2 t = tab[pos * 32 + p];
            csv[nt2][r] = t.x * QSCALE;
            snv[nt2][r] = t.y * QSCALE;
        }
    }
    const bool evn = !(tl & 1);
    int bb = tokw >> 11, pos0 = tokw & 2047;

    // GEMM2: C2[6] = qn @ wq_b^T (head h cols), B from LDS
    f4_t C2[6];
#pragma unroll
    for (int nt = 0; nt < 6; ++nt) C2[nt] = (f4_t){0.f, 0.f, 0.f, 0.f};
#pragma unroll
    for (int nt = 0; nt < 6; ++nt)
#pragma unroll
        for (int ks = 0; ks < 2; ++ks) {
            bf8_t bfr = *(const bf8_t*)(sB + (hh * 96 + nt * 16 + tl) * 72 + ks * 32 + qd * 8);
            C2[nt] = __builtin_amdgcn_mfma_f32_16x16x32_bf16(A2[ks], bfr, C2[nt], 0, 0, 0);
        }
    // q_nope bounce -> A-frag for absorb
#pragma unroll
    for (int nt = 0; nt < 2; ++nt)
#pragma unroll
        for (int r = 0; r < 4; ++r)
            qnb[(qd * 4 + r) * 40 + nt * 16 + tl] = f2bf(C2[nt][r]);
    bf8_t an = *(const bf8_t*)(qnb + tl * 40 + qd * 8);
    f4_t C3[4];
#pragma unroll
    for (int nt = 0; nt < 4; ++nt) C3[nt] = (f4_t){0.f, 0.f, 0.f, 0.f};
#pragma unroll
    for (int nt = 0; nt < 4; ++nt) {
        bf8_t bfr = *(const bf8_t*)(qabs + (size_t)h * 2048 + (nt * 16 + tl) * 32 + qd * 8);
        C3[nt] = __builtin_amdgcn_mfma_f32_16x16x32_bf16(an, bfr, C3[nt], 0, 0, 0);
    }
#pragma unroll
    for (int nt = 0; nt < 4; ++nt)
#pragma unroll
        for (int r = 0; r < 4; ++r)
            qf[(qd * 4 + r) * 136 + nt * 16 + tl] = f2bf(C3[nt][r]);
#pragma unroll
    for (int nt2 = 0; nt2 < 4; ++nt2) {
        int p = (nt2 * 16 + tl) >> 1;
        int outc = evn ? (64 + p) : (96 + p);
#pragma unroll
        for (int r = 0; r < 4; ++r) {
            float val = C2[nt2 + 2][r];
            float part = __shfl_xor(val, 1);
            float res = evn ? (val * csv[nt2][r] - part * snv[nt2][r])
                            : (val * csv[nt2][r] + part * snv[nt2][r]);
            qf[(qd * 4 + r) * 136 + outc] = f2bf(res);
        }
    }
    size_t qb = ((size_t)(bb * 8 + h) * 2048 + pos0) * 128;
#pragma unroll
    for (int i = 0; i < 4; ++i) {
        int idx = i * 64 + lane;
        int row = idx >> 4, c = idx & 15;
        uint4 v = *(const uint4*)(qf + row * 136 + c * 8);
        *(uint4*)(Qbf + qb + (size_t)row * 128 + c * 8) = v;
    }
}

// ---------------------------------------------------------------------------
// k3 v7.1: round-9 structure (2 barriers/tile, strides 136/72), 32 q/wave,
// NO-SHIFT exp2 softmax, cvt_pk P-pack, setprio. grid (16,8,4), 256 thr.
// ---------------------------------------------------------------------------
__global__ __launch_bounds__(256, 2) void k3_attn(
    const ushort_t* __restrict__ Qbf, const ushort_t* __restrict__ Kbf,
    const ushort_t* __restrict__ VTbf, const float* __restrict__ oaT,
    ushort_t* __restrict__ ctxb)
{
    __shared__ __align__(16) ushort_t LDS[22528];
    ushort_t* Kt = LDS;                    // [64][136]
    ushort_t* Vt = LDS + 8704;             // [64][72]
    ushort_t* Pw = LDS + 13312;            // [4][32][72]
    int j = threadIdx.x;
    int b = blockIdx.z, h = blockIdx.y, q0g = blockIdx.x * 128;
    int w = j >> 6, lane = j & 63;
    int tl = lane & 15, qd = lane >> 4;
    ushort_t* Pme = Pw + w * 2304;
    int qw = q0g + w * 32;

    bf8_t qfA[4], qfB[4];
    {
        const ushort_t* qp = Qbf + ((size_t)((b * 8 + h) * 2048) + qw + tl) * 128 + qd * 8;
#pragma unroll
        for (int ks = 0; ks < 4; ++ks) {
            qfA[ks] = *(const bf8_t*)(qp + ks * 32);
            qfB[ks] = *(const bf8_t*)(qp + 16 * 128 + ks * 32);
        }
    }
    f4_t OaccA[4], OaccB[4];
#pragma unroll
    for (int nt = 0; nt < 4; ++nt) {
        OaccA[nt] = (f4_t){0.f, 0.f, 0.f, 0.f};
        OaccB[nt] = (f4_t){0.f, 0.f, 0.f, 0.f};
    }
    float lA = 0.f, lB = 0.f;

    const size_t kbase = (size_t)b * 2048 * 128;
    const size_t vbase = (size_t)b * 64 * 2048;

    for (int it = 0; it < 32; ++it) {
        __syncthreads();
        {   // stage Kt: 256 thr x 32 shorts (4 x uint4)
            int r = j >> 2, c0 = (j & 3) * 32;
            const uint4* gp = (const uint4*)(Kbf + kbase + (size_t)(it * 64 + r) * 128 + c0);
            uint4 a0 = gp[0], a1 = gp[1], a2 = gp[2], a3 = gp[3];
            uint4* dp = (uint4*)(Kt + r * 136 + c0);
            dp[0] = a0; dp[1] = a1; dp[2] = a2; dp[3] = a3;
        }
        {   // stage Vt: 256 thr x 16 shorts (2 x uint4)
            int d = j >> 2, c0 = (j & 3) * 16;
            const uint4* gp = (const uint4*)(VTbf + vbase + (size_t)d * 2048 + it * 64 + c0);
            uint4 a0 = gp[0], a1 = gp[1];
            uint4* dp = (uint4*)(Vt + d * 72 + c0);
            dp[0] = a0; dp[1] = a1;
        }
        __syncthreads();
        // scores S^T for both groups; K-fragment shared
        f4_t SA[4], SB[4];
        __builtin_amdgcn_s_setprio(1);
#pragma unroll
        for (int nt = 0; nt < 4; ++nt) {
            f4_t cA = (f4_t){0.f, 0.f, 0.f, 0.f};
            f4_t cB = (f4_t){0.f, 0.f, 0.f, 0.f};
#pragma unroll
            for (int ks = 0; ks < 4; ++ks) {
                bf8_t kf = *(const bf8_t*)(Kt + (nt * 16 + tl) * 136 + ks * 32 + qd * 8);
                cA = __builtin_amdgcn_mfma_f32_16x16x32_bf16(kf, qfA[ks], cA, 0, 0, 0);
                cB = __builtin_amdgcn_mfma_f32_16x16x32_bf16(kf, qfB[ks], cB, 0, 0, 0);
            }
            SA[nt] = cA; SB[nt] = cB;
        }
        __builtin_amdgcn_s_setprio(0);
        // no-shift softmax: P = exp2(S); l += sum
        float rsA = 0.f, rsB = 0.f;
#pragma unroll
        for (int nt = 0; nt < 4; ++nt)
#pragma unroll
            for (int r = 0; r < 4; ++r) {
                float pA = fexp2(SA[nt][r]); SA[nt][r] = pA; rsA += pA;
                float pB = fexp2(SB[nt][r]); SB[nt][r] = pB; rsB += pB;
            }
        rsA += __shfl_xor(rsA, 16); rsA += __shfl_xor(rsA, 32);
        rsB += __shfl_xor(rsB, 16); rsB += __shfl_xor(rsB, 32);
        lA += rsA; lB += rsB;
        // P -> LDS via v_cvt_pk_bf16_f32
#pragma unroll
        for (int nt = 0; nt < 4; ++nt) {
            uint2 pkA, pkB;
            pkA.x = cvtpk_bf16(SA[nt][0], SA[nt][1]);
            pkA.y = cvtpk_bf16(SA[nt][2], SA[nt][3]);
            pkB.x = cvtpk_bf16(SB[nt][0], SB[nt][1]);
            pkB.y = cvtpk_bf16(SB[nt][2], SB[nt][3]);
            *(uint2*)(Pme + tl * 72 + nt * 16 + qd * 4) = pkA;
            *(uint2*)(Pme + (16 + tl) * 72 + nt * 16 + qd * 4) = pkB;
        }
        // PV
        bf8_t pfA[2], pfB[2];
#pragma unroll
        for (int ks = 0; ks < 2; ++ks) {
            pfA[ks] = *(const bf8_t*)(Pme + tl * 72 + ks * 32 + qd * 8);
            pfB[ks] = *(const bf8_t*)(Pme + (16 + tl) * 72 + ks * 32 + qd * 8);
        }
        __builtin_amdgcn_s_setprio(1);
#pragma unroll
        for (int nt = 0; nt < 4; ++nt)
#pragma unroll
            for (int ks = 0; ks < 2; ++ks) {
                bf8_t vf = *(const bf8_t*)(Vt + (nt * 16 + tl) * 72 + ks * 32 + qd * 8);
                OaccA[nt] = __builtin_amdgcn_mfma_f32_16x16x32_bf16(pfA[ks], vf, OaccA[nt], 0, 0, 0);
                OaccB[nt] = __builtin_amdgcn_mfma_f32_16x16x32_bf16(pfB[ks], vf, OaccB[nt], 0, 0, 0);
            }
        __builtin_amdgcn_s_setprio(0);
    }
    // normalize O into Pme rows 0..31
    {
        float linvA[4], linvB[4];
#pragma unroll
        for (int r = 0; r < 4; ++r) {
            float lqA = __shfl(lA, (lane & 48) + qd * 4 + r);
            float lqB = __shfl(lB, (lane & 48) + qd * 4 + r);
            linvA[r] = 1.f / lqA; linvB[r] = 1.f / lqB;
        }
#pragma unroll
        for (int nt = 0; nt < 4; ++nt)
#pragma unroll
            for (int r = 0; r < 4; ++r) {
                Pme[(qd * 4 + r) * 72 + nt * 16 + tl] = f2bf(OaccA[nt][r] * linvA[r]);
                Pme[(16 + qd * 4 + r) * 72 + nt * 16 + tl] = f2bf(OaccB[nt][r] * linvB[r]);
            }
    }
    __syncthreads();
    ushort_t* OA = LDS;  // [96][72]
    for (int e = j; e < 96 * 64; e += 256) {
        int v = e >> 6, r = e & 63;
        OA[v * 72 + r] = f2bf(oaT[h * 6144 + r * 96 + v]);
    }
    __syncthreads();
    {   // ctx[q][v] = sum_r O[q][r] * oa[r][v]
        bf8_t ofA[2], ofB[2];
#pragma unroll
        for (int ks = 0; ks < 2; ++ks) {
            ofA[ks] = *(const bf8_t*)(Pme + tl * 72 + ks * 32 + qd * 8);
            ofB[ks] = *(const bf8_t*)(Pme + (16 + tl) * 72 + ks * 32 + qd * 8);
        }
        __builtin_amdgcn_s_setprio(1);
#pragma unroll
        for (int nt = 0; nt < 6; ++nt) {
            f4_t cA = (f4_t){0.f, 0.f, 0.f, 0.f};
            f4_t cB = (f4_t){0.f, 0.f, 0.f, 0.f};
#pragma unroll
            for (int ks = 0; ks < 2; ++ks) {
                bf8_t af = *(const bf8_t*)(OA + (nt * 16 + tl) * 72 + ks * 32 + qd * 8);
                cA = __builtin_amdgcn_mfma_f32_16x16x32_bf16(ofA[ks], af, cA, 0, 0, 0);
                cB = __builtin_amdgcn_mfma_f32_16x16x32_bf16(ofB[ks], af, cB, 0, 0, 0);
            }
#pragma unroll
            for (int r = 0; r < 4; ++r) {
                size_t tokA = (size_t)(b * 2048 + qw + qd * 4 + r);
                size_t tokB = tokA + 16;
                ctxb[tokA * 768 + h * 96 + nt * 16 + tl] = f2bf(cA[r]);
                ctxb[tokB * 768 + h * 96 + nt * 16 + tl] = f2bf(cB[r]);
            }
        }
        __builtin_amdgcn_s_setprio(0);
    }
}

// ---------------------------------------------------------------------------
// k5a v2: LDS-tiled GEMM y = ctx @ wo^T + src -> ybf.
// ---------------------------------------------------------------------------
__global__ __launch_bounds__(512, 2) void k5a_gemm(
    const void* __restrict__ src, const void* __restrict__ nw,
    const float* __restrict__ ws,
    const ushort_t* __restrict__ ctxb, ushort_t* __restrict__ ybf)
{
    const ushort_t* woB = (const ushort_t*)(ws + OFF_WOT);
    const int isbf = get_isbf(nw);
    __shared__ __align__(16) ushort_t sB[384 * 72];   // 55296 B
    __shared__ __align__(16) ushort_t sA[32 * 72];    //  4608 B
    int j = threadIdx.x;
    int bx = blockIdx.x;
    int t0 = (bx >> 1) * 32;
    int colh = (bx & 1) * 384;
    int w = j >> 6, lane = j & 63;
    int tl = lane & 15, qd = lane >> 4;
    int mt = w & 1;
    int n0l = (w >> 1) * 96;          // wave's col offset within the 384

    f4_t acc[6];
#pragma unroll
    for (int nt = 0; nt < 6; ++nt) acc[nt] = (f4_t){0.f, 0.f, 0.f, 0.f};

    for (int kb = 0; kb < 12; ++kb) {
        __syncthreads();
        {   // stage B: wo rows colh..colh+383, cols kb*64..+63 (8 x uint4/row)
            for (int e = j; e < 384 * 8; e += 512) {
                int rr = e >> 3, ch = e & 7;
                uint4 v = *(const uint4*)(woB + (size_t)(colh + rr) * 768 + kb * 64 + ch * 8);
                *(uint4*)(sB + rr * 72 + ch * 8) = v;
            }
        }
        if (j < 256) {  // stage A: ctx rows t0..t0+31, cols kb*64..+63
            int rr = j >> 3, ch = j & 7;
            uint4 v = *(const uint4*)(ctxb + (size_t)(t0 + rr) * 768 + kb * 64 + ch * 8);
            *(uint4*)(sA + rr * 72 + ch * 8) = v;
        }
        __syncthreads();
        __builtin_amdgcn_s_setprio(1);
#pragma unroll
        for (int ks = 0; ks < 2; ++ks) {
            bf8_t a = *(const bf8_t*)(sA + (mt * 16 + tl) * 72 + ks * 32 + qd * 8);
#pragma unroll
            for (int nt = 0; nt < 6; ++nt) {
                bf8_t bfr = *(const bf8_t*)(sB + (n0l + nt * 16 + tl) * 72 + ks * 32 + qd * 8);
                acc[nt] = __builtin_amdgcn_mfma_f32_16x16x32_bf16(a, bfr, acc[nt], 0, 0, 0);
            }
        }
        __builtin_amdgcn_s_setprio(0);
    }
    // epilogue: residual add, store y bf16
#pragma unroll
    for (int nt = 0; nt < 6; ++nt)
#pragma unroll
        for (int r = 0; r < 4; ++r) {
            int row = t0 + mt * 16 + qd * 4 + r;
            int col = colh + n0l + nt * 16 + tl;
            float yv = acc[nt][r] + ldin(src, (size_t)row * 768 + col, isbf);
            ybf[(size_t)row * 768 + col] = f2bf(yv);
        }
}

// ---------------------------------------------------------------------------
// k5b: streaming RMSNorm y -> out. 16 tokens/block, grid 512, 256 thr.
// ---------------------------------------------------------------------------
__global__ __launch_bounds__(256) void k5b_norm(
    const void* __restrict__ nw_in, const float* __restrict__ ws,
    const ushort_t* __restrict__ ybf, void* __restrict__ out)
{
    const float* nw = ws + OFF_NW;
    const int isbf = get_isbf(nw_in);
    int j = threadIdx.x;
    int tt = j >> 4, s = j & 15;
    size_t row = (size_t)blockIdx.x * 16 + tt;
    const ushort_t* yp = ybf + row * 768 + s * 48;

    float val[48];
    float ss = 0.f;
#pragma unroll
    for (int c8 = 0; c8 < 6; ++c8) {
        union { uint4 u; ushort_t h[8]; } uu;
        uu.u = ((const uint4*)yp)[c8];
#pragma unroll
        for (int c = 0; c < 8; ++c) {
            float v = bf2f(uu.h[c]);
            val[c8 * 8 + c] = v;
            ss += v * v;
        }
    }
    ss += __shfl_xor(ss, 1); ss += __shfl_xor(ss, 2);
    ss += __shfl_xor(ss, 4); ss += __shfl_xor(ss, 8);
    float rs = rsqrtf(ss * (1.f / 768.f) + EPSF);
    const float* nwp = nw + s * 48;
    size_t base = row * 768 + s * 48;
    if (isbf) {
        ushort_t* op = (ushort_t*)out + base;
#pragma unroll
        for (int c8 = 0; c8 < 6; ++c8) {
            union { uint4 u; ushort_t h[8]; } uu;
#pragma unroll
            for (int c = 0; c < 8; ++c) {
                float hv = bf2f(f2bf(val[c8 * 8 + c] * rs));
                uu.h[c] = f2bf(hv * nwp[c8 * 8 + c]);
            }
            ((uint4*)op)[c8] = uu.u;
        }
    } else {
        float* op = (float*)out + base;
#pragma unroll
        for (int c4 = 0; c4 < 12; ++c4) {
            float4 f;
            f.x = val[c4 * 4 + 0] * rs * nwp[c4 * 4 + 0];
            f.y = val[c4 * 4 + 1] * rs * nwp[c4 * 4 + 1];
            f.z = val[c4 * 4 + 2] * rs * nwp[c4 * 4 + 2];
            f.w = val[c4 * 4 + 3] * rs * nwp[c4 * 4 + 3];
            ((float4*)op)[c4] = f;
        }
    }
}

// ---------------------------------------------------------------------------
extern "C" void kernel_launch(void* const* d_in, const int* in_sizes, int n_in,
                              void* d_out, int out_size, void* d_ws, size_t ws_size,
                              hipStream_t stream)
{
    const void* src   = d_in[0];
    const void* wq_a  = d_in[1];
    const void* q_ln  = d_in[2];
    const void* wq_b  = d_in[3];
    const void* wkv_a = d_in[4];
    const void* kv_ln = d_in[5];
    const void* wkv_b = d_in[6];
    const void* wo    = d_in[7];
    const void* nw    = d_in[8];
    float* ws = (float*)d_ws;
    ushort_t* Kbf   = (ushort_t*)(ws + OFF_KBF);
    ushort_t* VTbf  = (ushort_t*)(ws + OFF_VTB);
    ushort_t* Qbf   = (ushort_t*)(ws + OFF_QBF);
    ushort_t* ctxb  = (ushort_t*)(ws + OFF_CTXF);
    ushort_t* ybf   = Qbf;   // Q' dead after k3; reuse as y [8192][768]
    ushort_t* qn    = ctxb;  // ctx region dead until k3; reuse as qn [8192][64]

    prep_k<<<dim3(PB7), dim3(256), 0, stream>>>(wq_a, q_ln, wq_b, wkv_a, kv_ln, wkv_b, wo, nw, ws);
    k1_ckv<<<dim3(TOK / 32), dim3(512), 0, stream>>>(src, nw, ws, Kbf, VTbf, qn);
    k2b_q<<<dim3(TOK / 32 * 2), dim3(512), 0, stream>>>(ws, qn, Qbf);
    k3_attn<<<dim3(16, 8, 4), dim3(256), 0, stream>>>(Qbf, Kbf, VTbf, ws + OFF_OAT, ctxb);
    k5a_gemm<<<dim3(TOK / 32 * 2), dim3(512), 0, stream>>>(src, nw, ws, ctxb, ybf);
    k5b_norm<<<dim3(TOK / 16), dim3(256), 0, stream>>>(nw, ws, ybf, d_out);
}

// Round 16
// 244.053 us; speedup vs baseline: 1.0662x; 1.0336x over previous
//
#include <hip/hip_runtime.h>

// ---------------------------------------------------------------------------
// MLA prefill (B=4, S=2048, D=768, H=8, q_rank=kv_rank=rope=64, nope=32, v=96)
// Round 25:
//  - k1 reverted to v3 (round-22 exact: direct-global B with unroll 4;
//    v4's LDS-staged B added 24 barriers @ 2 MFMAs each -> +10us, refuted).
//  - out_absorbT pre-converted to bf16 in prep ([h][v][r] at dead SRCBF
//    offset); k3's OA stage is now a pure uint4 copy (was 6144 fp32 loads
//    + f2bf per block). Bit-identical (same f2bf, applied once in prep).
// k3 v7.1 / k2b / k5a / k5b = round-22 exact (248.2us verified; k3 code
// measured 89.5 and 83.4 across runs -> ~6us run variance).
// ---------------------------------------------------------------------------

#define DEV static __device__ __forceinline__
typedef unsigned short ushort_t;
typedef __attribute__((ext_vector_type(8))) short bf8_t;
typedef __attribute__((ext_vector_type(4))) float f4_t;

DEV float bf2f(unsigned int u) {
    union { float f; unsigned int i; } x; x.i = u << 16; return x.f;
}
DEV ushort_t f2bf(float f) {
    union { float f; unsigned int u; } x; x.f = f;
    unsigned int u = x.u;
    return (ushort_t)((u + 0x7fffu + ((u >> 16) & 1u)) >> 16);
}
DEV unsigned cvtpk_bf16(float lo, float hi) {   // packed f32x2 -> bf16x2, RNE
    unsigned r;
    asm("v_cvt_pk_bf16_f32 %0, %1, %2" : "=v"(r) : "v"(lo), "v"(hi));
    return r;
}
DEV float ldin(const void* p, size_t i, int isbf) {
    return isbf ? bf2f(((const ushort_t*)p)[i]) : ((const float*)p)[i];
}
DEV float fexp2(float x) {
#if __has_builtin(__builtin_amdgcn_exp2f)
    return __builtin_amdgcn_exp2f(x);
#else
    return exp2f(x);
#endif
}
DEV int get_isbf(const void* nw) {
    return ((((const unsigned int*)nw)[0] & 0xffffu) != 0u) ? 1 : 0;
}

constexpr int   TOK   = 4 * 2048;                         // 8192 tokens
constexpr float EPSF  = 1e-6f;
// Q' carries SCALE*log2(e) so softmax uses native exp2
constexpr float QSCALE = (float)(0.10206207261596575 * 1.4426950408889634);
constexpr float L2_10000_OVER_32 = 0.4152410118609203f;   // log2(10000)/32

// workspace layout (float offsets)
constexpr size_t OFF_WOT   = 0;                 // wo bf16 [768][768]
constexpr size_t OFF_WKVAT = 589824;            // wkv_a bf16 [128][768] (k1 B)
constexpr size_t OFF_WQAT  = 688128;            // wq_a bf16 [64][768] (k1 qn B)
constexpr size_t OFF_WQBT  = 737280;            // wq_b bf16 [768][64] (k2b B)
constexpr size_t OFF_QAF   = 786432;            // q_absorbT*QSCALE bf16 [8][64][32]
constexpr size_t OFF_OAT   = 802816;            // (fp32 copy, unused since r25)
constexpr size_t OFF_QLN   = 851968;
constexpr size_t OFF_KVLN  = 852032;
constexpr size_t OFF_NW    = 852096;
constexpr size_t OFF_FLAG  = 852864;            // (unused since round 12)
constexpr size_t OFF_CTXF  = 852880;            // ctx bf16 [8192][768]; qn bf16 [8192][64] before k3
constexpr size_t OFF_OATB  = 3998608;           // out_absorbT bf16 [8][96][64] (was srcbf, dead)
constexpr size_t OFF_KBF   = 7144336;           // K' bf16 [4][2048][128]
constexpr size_t OFF_VTB   = 7668624;           // V^T bf16 [4][64][2048]
constexpr size_t OFF_QBF   = 7930768;           // Q' bf16 [4][8][2048][128]; y bf16 [8192][768] after k3
constexpr size_t OFF_ROPE  = 12125072;          // rope table float2 [2048][32]

// prep 1D-grid segment offsets (256-thr blocks)
constexpr int PB0 = 2304;            // wo copy        [0, 2304)
constexpr int PB1 = PB0 + 384;       // wkv_a          [2304, 2688)
constexpr int PB2 = PB1 + 192;       // wq_a           [2688, 2880)
constexpr int PB3 = PB2 + 192;       // wq_b           [2880, 3072)
constexpr int PB4 = PB3 + 64;        // q_absorbT      [3072, 3136)
constexpr int PB5 = PB4 + 192;       // out_absorbT bf16 [3136, 3328)
constexpr int PB6 = PB5 + 4;         // norm vectors   [3328, 3332)
constexpr int PB7 = PB6 + 256;       // rope table     [3332, 3588)

// ---------------------------------------------------------------------------
__global__ __launch_bounds__(256) void prep_k(
    const void* __restrict__ wq_a, const void* __restrict__ q_ln,
    const void* __restrict__ wq_b, const void* __restrict__ wkv_a,
    const void* __restrict__ kv_ln, const void* __restrict__ wkv_b,
    const void* __restrict__ wo, const void* __restrict__ nw,
    float* __restrict__ ws)
{
    const int isbf = get_isbf(nw);
    const int bid = blockIdx.x;
    const int tid = threadIdx.x;
    if (bid < PB0) {        // wo -> bf16 straight copy
        int i = bid * 256 + tid;
        ushort_t* wob = (ushort_t*)(ws + OFF_WOT);
        wob[i] = isbf ? ((const ushort_t*)wo)[i] : f2bf(((const float*)wo)[i]);
    } else if (bid < PB1) { // wkv_a bf16 straight [128][768]
        int i = (bid - PB0) * 256 + tid;
        ushort_t* d = (ushort_t*)(ws + OFF_WKVAT);
        d[i] = isbf ? ((const ushort_t*)wkv_a)[i] : f2bf(((const float*)wkv_a)[i]);
    } else if (bid < PB2) { // wq_a bf16 straight [64][768]
        int i = (bid - PB1) * 256 + tid;
        ushort_t* d = (ushort_t*)(ws + OFF_WQAT);
        d[i] = isbf ? ((const ushort_t*)wq_a)[i] : f2bf(((const float*)wq_a)[i]);
    } else if (bid < PB3) { // wq_b bf16 straight [768][64]
        int i = (bid - PB2) * 256 + tid;
        ushort_t* d = (ushort_t*)(ws + OFF_WQBT);
        d[i] = isbf ? ((const ushort_t*)wq_b)[i] : f2bf(((const float*)wq_b)[i]);
    } else if (bid < PB4) { // q_absorbT * QSCALE bf16 [8][r=64][d=32]
        int i = (bid - PB3) * 256 + tid;
        int h = i >> 11, rem = i & 2047, r = rem >> 5, d = rem & 31;
        ushort_t* dst = (ushort_t*)(ws + OFF_QAF);
        dst[i] = f2bf(ldin(wkv_b, (size_t)(h * 128 + d) * 64 + r, isbf) * QSCALE);
    } else if (bid < PB5) { // out_absorbT bf16 [h][v][r] (straight rows 32..127)
        int i = (bid - PB4) * 256 + tid;      // i < 8*96*64
        int h = i / 6144, i2 = i - h * 6144;  // i2 = v*64 + r
        ushort_t* dst = (ushort_t*)(ws + OFF_OATB);
        dst[i] = f2bf(ldin(wkv_b, (size_t)h * 8192 + 2048 + i2, isbf));
    } else if (bid < PB6) { // norm vectors (896 elements)
        int i = (bid - PB5) * 256 + tid;
        if (i < 64)             ws[OFF_QLN + i]       = ldin(q_ln, i, isbf);
        else if (i < 128)       ws[OFF_KVLN + i - 64] = ldin(kv_ln, i - 64, isbf);
        else if (i < 128 + 768) ws[OFF_NW + i - 128]  = ldin(nw, i - 128, isbf);
    } else {                // rope table [pos][p] = (cos, sin)
        int i = (bid - PB6) * 256 + tid;
        int pos = i >> 5, p = i & 31;
        float inv = exp2f(-(float)p * L2_10000_OVER_32);
        float ang = (float)pos * inv;
        float2* tab = (float2*)(ws + OFF_ROPE);
        tab[i] = make_float2(cosf(ang), sinf(ang));
    }
}

// ---------------------------------------------------------------------------
// k1 v3: MFMA ckv GEMM (B direct from global/L2, unroll 4) + epilogue +
// merged qn pass (waves 0-1, from sA). Round-22 exact.
// ---------------------------------------------------------------------------
__global__ __launch_bounds__(512) void k1_ckv(
    const void* __restrict__ src, const void* __restrict__ nw,
    const float* __restrict__ ws,
    ushort_t* __restrict__ Kbf, ushort_t* __restrict__ VTbf,
    ushort_t* __restrict__ qn_all)
{
    const ushort_t* wkvab = (const ushort_t*)(ws + OFF_WKVAT);  // [128][768]
    const ushort_t* wqab  = (const ushort_t*)(ws + OFF_WQAT);   // [64][768]
    const float* kvln  = ws + OFF_KVLN;
    const float* qln   = ws + OFF_QLN;
    const float2* tab  = (const float2*)(ws + OFF_ROPE);
    const int isbf = get_isbf(nw);
    __shared__ __align__(16) ushort_t sA[32 * 776];
    __shared__ __align__(16) float ckv[32][132];
    int j = threadIdx.x;
    int t0 = blockIdx.x * 32;
    int w = j >> 6, lane = j & 63;
    int tl = lane & 15, qd = lane >> 4;

    {   // stage A: src[t0..t0+31][0..767] -> sA bf16 (stride 776)
        for (int e = j; e < 32 * 96; e += 512) {
            int row = e / 96, c8 = e - row * 96;
            size_t off = (size_t)(t0 + row) * 768 + c8 * 8;
            if (isbf) {
                uint4 v = *(const uint4*)((const ushort_t*)src + off);
                *(uint4*)(sA + row * 776 + c8 * 8) = v;
            } else {
                const float4* p = (const float4*)((const float*)src + off);
                float4 f0 = p[0], f1 = p[1];
                ushort_t tmp[8] = {f2bf(f0.x), f2bf(f0.y), f2bf(f0.z), f2bf(f0.w),
                                   f2bf(f1.x), f2bf(f1.y), f2bf(f1.z), f2bf(f1.w)};
                uint4 v = *(const uint4*)tmp;
                *(uint4*)(sA + row * 776 + c8 * 8) = v;
            }
        }
    }
    __syncthreads();
    {   // GEMM: ckv[32][128] = A @ wkv_a^T, wave w owns cols w*16..w*16+15
        f4_t acc[2];
        acc[0] = (f4_t){0.f, 0.f, 0.f, 0.f};
        acc[1] = (f4_t){0.f, 0.f, 0.f, 0.f};
        const ushort_t* bp = wkvab + (size_t)(w * 16 + tl) * 768 + qd * 8;
#pragma unroll 4
        for (int ks = 0; ks < 24; ++ks) {
            bf8_t b  = *(const bf8_t*)(bp + ks * 32);
            bf8_t a0 = *(const bf8_t*)(sA + tl * 776 + ks * 32 + qd * 8);
            bf8_t a1 = *(const bf8_t*)(sA + (16 + tl) * 776 + ks * 32 + qd * 8);
            acc[0] = __builtin_amdgcn_mfma_f32_16x16x32_bf16(a0, b, acc[0], 0, 0, 0);
            acc[1] = __builtin_amdgcn_mfma_f32_16x16x32_bf16(a1, b, acc[1], 0, 0, 0);
        }
#pragma unroll
        for (int mt = 0; mt < 2; ++mt)
#pragma unroll
            for (int r = 0; r < 4; ++r)
                ckv[mt * 16 + qd * 4 + r][w * 16 + tl] = acc[mt][r];
    }
    __syncthreads();

    if (j < 256) {
        int tt = j >> 3, l = j & 7;
        float ss = 0.f;
#pragma unroll
        for (int i = 0; i < 8; ++i) { float v = ckv[tt][l * 8 + i]; ss += v * v; }
        ss += __shfl_xor(ss, 1); ss += __shfl_xor(ss, 2); ss += __shfl_xor(ss, 4);
        float rs = rsqrtf(ss * (1.f / 64.f) + EPSF);
        size_t base = (size_t)(t0 + tt) * 128;
        ushort_t kb[8];
        float clw[8];
#pragma unroll
        for (int i = 0; i < 8; ++i) {
            int o2 = l * 8 + i;
            float cl = ckv[tt][o2] * rs;
            if (isbf) cl = bf2f(f2bf(cl));   // reference: .astype(bf16) before *w
            clw[i] = cl * kvln[o2];
            kb[i] = f2bf(clw[i]);
        }
        uint4 pack;
        pack.x = kb[0] | ((unsigned)kb[1] << 16); pack.y = kb[2] | ((unsigned)kb[3] << 16);
        pack.z = kb[4] | ((unsigned)kb[5] << 16); pack.w = kb[6] | ((unsigned)kb[7] << 16);
        *(uint4*)&Kbf[base + l * 8] = pack;
        int pos = (t0 + tt) & 2047;
        ushort_t r0[4], r1[4];
#pragma unroll
        for (int i = 0; i < 4; ++i) {
            int p = l * 4 + i;
            float2 cssn = tab[pos * 32 + p];
            float e = ckv[tt][64 + 2 * p], od = ckv[tt][64 + 2 * p + 1];
            r0[i] = f2bf(e * cssn.x - od * cssn.y);
            r1[i] = f2bf(od * cssn.x + e * cssn.y);
        }
        uint2 p0, p1;
        p0.x = r0[0] | ((unsigned)r0[1] << 16); p0.y = r0[2] | ((unsigned)r0[3] << 16);
        p1.x = r1[0] | ((unsigned)r1[1] << 16); p1.y = r1[2] | ((unsigned)r1[3] << 16);
        *(uint2*)&Kbf[base + 64 + l * 4] = p0;
        *(uint2*)&Kbf[base + 96 + l * 4] = p1;
#pragma unroll
        for (int i = 0; i < 8; ++i) ckv[tt][l * 8 + i] = clw[i];
    }
    __syncthreads();
    if (j < 256) {   // VT[b][r][t] = c_lat_n[t][r]
        int t = j & 31, rb = (j >> 5) * 8;
        int bb = t0 >> 11, col = (t0 & 2047) + t;
#pragma unroll
        for (int i = 0; i < 8; ++i) {
            int r = rb + i;
            VTbf[((size_t)(bb * 64 + r)) * 2048 + col] = f2bf(ckv[t][r]);
        }
    }
    __syncthreads();   // ckv free for reuse as qn bounce
    if (w < 2) {       // merged qn pass: wave w -> tokens t0 + w*16 .. +15
        f4_t C1[4];
#pragma unroll
        for (int nt = 0; nt < 4; ++nt) C1[nt] = (f4_t){0.f, 0.f, 0.f, 0.f};
        const ushort_t* ap = sA + (size_t)(w * 16 + tl) * 776 + qd * 8;
#pragma unroll 4
        for (int ks = 0; ks < 24; ++ks) {
            bf8_t a = *(const bf8_t*)(ap + ks * 32);
#pragma unroll
            for (int nt = 0; nt < 4; ++nt) {
                bf8_t bfr = *(const bf8_t*)(wqab + (size_t)(nt * 16 + tl) * 768 + ks * 32 + qd * 8);
                C1[nt] = __builtin_amdgcn_mfma_f32_16x16x32_bf16(a, bfr, C1[nt], 0, 0, 0);
            }
        }
        float rsv[4];
#pragma unroll
        for (int r = 0; r < 4; ++r) {
            float s = C1[0][r] * C1[0][r] + C1[1][r] * C1[1][r]
                    + C1[2][r] * C1[2][r] + C1[3][r] * C1[3][r];
            s += __shfl_xor(s, 1); s += __shfl_xor(s, 2);
            s += __shfl_xor(s, 4); s += __shfl_xor(s, 8);
            rsv[r] = rsqrtf(s * (1.f / 64.f) + EPSF);
        }
        float qlnv[4];
#pragma unroll
        for (int nt = 0; nt < 4; ++nt) qlnv[nt] = qln[nt * 16 + tl];
        ushort_t* tmpn = (ushort_t*)&ckv[0][0] + w * 1152;
#pragma unroll
        for (int nt = 0; nt < 4; ++nt)
#pragma unroll
            for (int r = 0; r < 4; ++r) {
                float v = C1[nt][r] * rsv[r];
                if (isbf) v = bf2f(f2bf(v));  // .astype(bf16) before *w
                tmpn[(qd * 4 + r) * 72 + nt * 16 + tl] = f2bf(v * qlnv[nt]);
            }
#pragma unroll
        for (int i = 0; i < 2; ++i) {
            int e = i * 64 + lane;
            int row = e >> 3, ch = e & 7;
            uint4 v = *(const uint4*)(tmpn + row * 72 + ch * 8);
            *(uint4*)(qn_all + (size_t)(t0 + w * 16 + row) * 64 + ch * 8) = v;
        }
    }
}

// ---------------------------------------------------------------------------
// k2b: Q' = rope/absorb(qn @ wq_b^T). Block = 32 tok x 384 cols (4 heads),
// 512 thr (8 waves); wave = 16 tok x 1 head. wq_b staged once in LDS.
// ---------------------------------------------------------------------------
__global__ __launch_bounds__(512) void k2b_q(
    const float* __restrict__ ws, const ushort_t* __restrict__ qn_all,
    ushort_t* __restrict__ Qbf)
{
    const ushort_t* wqbb = (const ushort_t*)(ws + OFF_WQBT);   // [768][64]
    const ushort_t* qabs = (const ushort_t*)(ws + OFF_QAF);    // [8][64][32] *QSCALE
    const float2*   tab  = (const float2*)(ws + OFF_ROPE);

    __shared__ __align__(16) ushort_t sB[384 * 72];    // 27648 sh
    __shared__ __align__(16) ushort_t sA[32 * 72];     //  2304 sh
    __shared__ __align__(16) ushort_t PW[8 * 2816];    // per wave: qn 640 + qf 2176
    int j = threadIdx.x;
    int bx = blockIdx.x;
    int t0 = (bx >> 1) * 32;
    int colh = (bx & 1) * 384;
    int w = j >> 6, lane = j & 63;
    int tl = lane & 15, qd = lane >> 4;
    int mt = w & 1, hh = w >> 1;
    int h = (bx & 1) * 4 + hh;
    ushort_t* qnb = PW + w * 2816;
    ushort_t* qf  = qnb + 640;
    int tokw = t0 + mt * 16;

    {   // stage B: wq_b rows colh..colh+383 x 64 k (384 x 8 uint4)
        for (int e = j; e < 384 * 8; e += 512) {
            int rr = e >> 3, ch = e & 7;
            uint4 v = *(const uint4*)(wqbb + (size_t)(colh + rr) * 64 + ch * 8);
            *(uint4*)(sB + rr * 72 + ch * 8) = v;
        }
    }
    if (j < 256) {  // stage A: qn rows t0..t0+31 x 64
        int rr = j >> 3, ch = j & 7;
        uint4 v = *(const uint4*)(qn_all + (size_t)(t0 + rr) * 64 + ch * 8);
        *(uint4*)(sA + rr * 72 + ch * 8) = v;
    }
    __syncthreads();

    bf8_t A2[2];
#pragma unroll
    for (int ks = 0; ks < 2; ++ks)
        A2[ks] = *(const bf8_t*)(sA + (mt * 16 + tl) * 72 + ks * 32 + qd * 8);

    // rope cos/sin preload, scaled by QSCALE
    float csv[4][4], snv[4][4];
#pragma unroll
    for (int nt2 = 0; nt2 < 4; ++nt2) {
        int p = (nt2 * 16 + tl) >> 1;
#pragma unroll
        for (int r = 0; r < 4; ++r) {
            int pos = (tokw + qd * 4 + r) & 2047;
            float2 t = tab[pos * 32 + p];
            csv[nt2][r] = t.x * QSCALE;
            snv[nt2][r] = t.y * QSCALE;
        }
    }
    const bool evn = !(tl & 1);
    int bb = tokw >> 11, pos0 = tokw & 2047;

    // GEMM2: C2[6] = qn @ wq_b^T (head h cols), B from LDS
    f4_t C2[6];
#pragma unroll
    for (int nt = 0; nt < 6; ++nt) C2[nt] = (f4_t){0.f, 0.f, 0.f, 0.f};
#pragma unroll
    for (int nt = 0; nt < 6; ++nt)
#pragma unroll
        for (int ks = 0; ks < 2; ++ks) {
            bf8_t bfr = *(const bf8_t*)(sB + (hh * 96 + nt * 16 + tl) * 72 + ks * 32 + qd * 8);
            C2[nt] = __builtin_amdgcn_mfma_f32_16x16x32_bf16(A2[ks], bfr, C2[nt], 0, 0, 0);
        }
    // q_nope bounce -> A-frag for absorb
#pragma unroll
    for (int nt = 0; nt < 2; ++nt)
#pragma unroll
        for (int r = 0; r < 4; ++r)
            qnb[(qd * 4 + r) * 40 + nt * 16 + tl] = f2bf(C2[nt][r]);
    bf8_t an = *(const bf8_t*)(qnb + tl * 40 + qd * 8);
    f4_t C3[4];
#pragma unroll
    for (int nt = 0; nt < 4; ++nt) C3[nt] = (f4_t){0.f, 0.f, 0.f, 0.f};
#pragma unroll
    for (int nt = 0; nt < 4; ++nt) {
        bf8_t bfr = *(const bf8_t*)(qabs + (size_t)h * 2048 + (nt * 16 + tl) * 32 + qd * 8);
        C3[nt] = __builtin_amdgcn_mfma_f32_16x16x32_bf16(an, bfr, C3[nt], 0, 0, 0);
    }
#pragma unroll
    for (int nt = 0; nt < 4; ++nt)
#pragma unroll
        for (int r = 0; r < 4; ++r)
            qf[(qd * 4 + r) * 136 + nt * 16 + tl] = f2bf(C3[nt][r]);
#pragma unroll
    for (int nt2 = 0; nt2 < 4; ++nt2) {
        int p = (nt2 * 16 + tl) >> 1;
        int outc = evn ? (64 + p) : (96 + p);
#pragma unroll
        for (int r = 0; r < 4; ++r) {
            float val = C2[nt2 + 2][r];
            float part = __shfl_xor(val, 1);
            float res = evn ? (val * csv[nt2][r] - part * snv[nt2][r])
                            : (val * csv[nt2][r] + part * snv[nt2][r]);
            qf[(qd * 4 + r) * 136 + outc] = f2bf(res);
        }
    }
    size_t qb = ((size_t)(bb * 8 + h) * 2048 + pos0) * 128;
#pragma unroll
    for (int i = 0; i < 4; ++i) {
        int idx = i * 64 + lane;
        int row = idx >> 4, c = idx & 15;
        uint4 v = *(const uint4*)(qf + row * 136 + c * 8);
        *(uint4*)(Qbf + qb + (size_t)row * 128 + c * 8) = v;
    }
}

// ---------------------------------------------------------------------------
// k3 v7.2: round-9 structure (2 barriers/tile, strides 136/72), 32 q/wave,
// NO-SHIFT exp2 softmax, cvt_pk P-pack, setprio. OA staged from bf16 oaTb
// (pure uint4 copy). grid (16,8,4), 256 thr.
// ---------------------------------------------------------------------------
__global__ __launch_bounds__(256, 2) void k3_attn(
    const ushort_t* __restrict__ Qbf, const ushort_t* __restrict__ Kbf,
    const ushort_t* __restrict__ VTbf, const ushort_t* __restrict__ oaTb,
    ushort_t* __restrict__ ctxb)
{
    __shared__ __align__(16) ushort_t LDS[22528];
    ushort_t* Kt = LDS;                    // [64][136]
    ushort_t* Vt = LDS + 8704;             // [64][72]
    ushort_t* Pw = LDS + 13312;            // [4][32][72]
    int j = threadIdx.x;
    int b = blockIdx.z, h = blockIdx.y, q0g = blockIdx.x * 128;
    int w = j >> 6, lane = j & 63;
    int tl = lane & 15, qd = lane >> 4;
    ushort_t* Pme = Pw + w * 2304;
    int qw = q0g + w * 32;

    bf8_t qfA[4], qfB[4];
    {
        const ushort_t* qp = Qbf + ((size_t)((b * 8 + h) * 2048) + qw + tl) * 128 + qd * 8;
#pragma unroll
        for (int ks = 0; ks < 4; ++ks) {
            qfA[ks] = *(const bf8_t*)(qp + ks * 32);
            qfB[ks] = *(const bf8_t*)(qp + 16 * 128 + ks * 32);
        }
    }
    f4_t OaccA[4], OaccB[4];
#pragma unroll
    for (int nt = 0; nt < 4; ++nt) {
        OaccA[nt] = (f4_t){0.f, 0.f, 0.f, 0.f};
        OaccB[nt] = (f4_t){0.f, 0.f, 0.f, 0.f};
    }
    float lA = 0.f, lB = 0.f;

    const size_t kbase = (size_t)b * 2048 * 128;
    const size_t vbase = (size_t)b * 64 * 2048;

    for (int it = 0; it < 32; ++it) {
        __syncthreads();
        {   // stage Kt: 256 thr x 32 shorts (4 x uint4)
            int r = j >> 2, c0 = (j & 3) * 32;
            const uint4* gp = (const uint4*)(Kbf + kbase + (size_t)(it * 64 + r) * 128 + c0);
            uint4 a0 = gp[0], a1 = gp[1], a2 = gp[2], a3 = gp[3];
            uint4* dp = (uint4*)(Kt + r * 136 + c0);
            dp[0] = a0; dp[1] = a1; dp[2] = a2; dp[3] = a3;
        }
        {   // stage Vt: 256 thr x 16 shorts (2 x uint4)
            int d = j >> 2, c0 = (j & 3) * 16;
            const uint4* gp = (const uint4*)(VTbf + vbase + (size_t)d * 2048 + it * 64 + c0);
            uint4 a0 = gp[0], a1 = gp[1];
            uint4* dp = (uint4*)(Vt + d * 72 + c0);
            dp[0] = a0; dp[1] = a1;
        }
        __syncthreads();
        // scores S^T for both groups; K-fragment shared
        f4_t SA[4], SB[4];
        __builtin_amdgcn_s_setprio(1);
#pragma unroll
        for (int nt = 0; nt < 4; ++nt) {
            f4_t cA = (f4_t){0.f, 0.f, 0.f, 0.f};
            f4_t cB = (f4_t){0.f, 0.f, 0.f, 0.f};
#pragma unroll
            for (int ks = 0; ks < 4; ++ks) {
                bf8_t kf = *(const bf8_t*)(Kt + (nt * 16 + tl) * 136 + ks * 32 + qd * 8);
                cA = __builtin_amdgcn_mfma_f32_16x16x32_bf16(kf, qfA[ks], cA, 0, 0, 0);
                cB = __builtin_amdgcn_mfma_f32_16x16x32_bf16(kf, qfB[ks], cB, 0, 0, 0);
            }
            SA[nt] = cA; SB[nt] = cB;
        }
        __builtin_amdgcn_s_setprio(0);
        // no-shift softmax: P = exp2(S); l += sum
        float rsA = 0.f, rsB = 0.f;
#pragma unroll
        for (int nt = 0; nt < 4; ++nt)
#pragma unroll
            for (int r = 0; r < 4; ++r) {
                float pA = fexp2(SA[nt][r]); SA[nt][r] = pA; rsA += pA;
                float pB = fexp2(SB[nt][r]); SB[nt][r] = pB; rsB += pB;
            }
        rsA += __shfl_xor(rsA, 16); rsA += __shfl_xor(rsA, 32);
        rsB += __shfl_xor(rsB, 16); rsB += __shfl_xor(rsB, 32);
        lA += rsA; lB += rsB;
        // P -> LDS via v_cvt_pk_bf16_f32
#pragma unroll
        for (int nt = 0; nt < 4; ++nt) {
            uint2 pkA, pkB;
            pkA.x = cvtpk_bf16(SA[nt][0], SA[nt][1]);
            pkA.y = cvtpk_bf16(SA[nt][2], SA[nt][3]);
            pkB.x = cvtpk_bf16(SB[nt][0], SB[nt][1]);
            pkB.y = cvtpk_bf16(SB[nt][2], SB[nt][3]);
            *(uint2*)(Pme + tl * 72 + nt * 16 + qd * 4) = pkA;
            *(uint2*)(Pme + (16 + tl) * 72 + nt * 16 + qd * 4) = pkB;
        }
        // PV
        bf8_t pfA[2], pfB[2];
#pragma unroll
        for (int ks = 0; ks < 2; ++ks) {
            pfA[ks] = *(const bf8_t*)(Pme + tl * 72 + ks * 32 + qd * 8);
            pfB[ks] = *(const bf8_t*)(Pme + (16 + tl) * 72 + ks * 32 + qd * 8);
        }
        __builtin_amdgcn_s_setprio(1);
#pragma unroll
        for (int nt = 0; nt < 4; ++nt)
#pragma unroll
            for (int ks = 0; ks < 2; ++ks) {
                bf8_t vf = *(const bf8_t*)(Vt + (nt * 16 + tl) * 72 + ks * 32 + qd * 8);
                OaccA[nt] = __builtin_amdgcn_mfma_f32_16x16x32_bf16(pfA[ks], vf, OaccA[nt], 0, 0, 0);
                OaccB[nt] = __builtin_amdgcn_mfma_f32_16x16x32_bf16(pfB[ks], vf, OaccB[nt], 0, 0, 0);
            }
        __builtin_amdgcn_s_setprio(0);
    }
    // normalize O into Pme rows 0..31
    {
        float linvA[4], linvB[4];
#pragma unroll
        for (int r = 0; r < 4; ++r) {
            float lqA = __shfl(lA, (lane & 48) + qd * 4 + r);
            float lqB = __shfl(lB, (lane & 48) + qd * 4 + r);
            linvA[r] = 1.f / lqA; linvB[r] = 1.f / lqB;
        }
#pragma unroll
        for (int nt = 0; nt < 4; ++nt)
#pragma unroll
            for (int r = 0; r < 4; ++r) {
                Pme[(qd * 4 + r) * 72 + nt * 16 + tl] = f2bf(OaccA[nt][r] * linvA[r]);
                Pme[(16 + qd * 4 + r) * 72 + nt * 16 + tl] = f2bf(OaccB[nt][r] * linvB[r]);
            }
    }
    __syncthreads();
    ushort_t* OA = LDS;  // [96][72]
    {   // stage OA from bf16 oaTb [h][v][r]: pure uint4 copy (768 x 16B)
        const ushort_t* oap = oaTb + (size_t)h * 6144;
        for (int e = j; e < 768; e += 256) {
            int idx = e * 8;
            int v = idx >> 6, r = idx & 63;
            *(uint4*)(OA + v * 72 + r) = *(const uint4*)(oap + idx);
        }
    }
    __syncthreads();
    {   // ctx[q][v] = sum_r O[q][r] * oa[r][v]
        bf8_t ofA[2], ofB[2];
#pragma unroll
        for (int ks = 0; ks < 2; ++ks) {
            ofA[ks] = *(const bf8_t*)(Pme + tl * 72 + ks * 32 + qd * 8);
            ofB[ks] = *(const bf8_t*)(Pme + (16 + tl) * 72 + ks * 32 + qd * 8);
        }
        __builtin_amdgcn_s_setprio(1);
#pragma unroll
        for (int nt = 0; nt < 6; ++nt) {
            f4_t cA = (f4_t){0.f, 0.f, 0.f, 0.f};
            f4_t cB = (f4_t){0.f, 0.f, 0.f, 0.f};
#pragma unroll
            for (int ks = 0; ks < 2; ++ks) {
                bf8_t af = *(const bf8_t*)(OA + (nt * 16 + tl) * 72 + ks * 32 + qd * 8);
                cA = __builtin_amdgcn_mfma_f32_16x16x32_bf16(ofA[ks], af, cA, 0, 0, 0);
                cB = __builtin_amdgcn_mfma_f32_16x16x32_bf16(ofB[ks], af, cB, 0, 0, 0);
            }
#pragma unroll
            for (int r = 0; r < 4; ++r) {
                size_t tokA = (size_t)(b * 2048 + qw + qd * 4 + r);
                size_t tokB = tokA + 16;
                ctxb[tokA * 768 + h * 96 + nt * 16 + tl] = f2bf(cA[r]);
                ctxb[tokB * 768 + h * 96 + nt * 16 + tl] = f2bf(cB[r]);
            }
        }
        __builtin_amdgcn_s_setprio(0);
    }
}

// ---------------------------------------------------------------------------
// k5a v2: LDS-tiled GEMM y = ctx @ wo^T + src -> ybf.
// ---------------------------------------------------------------------------
__global__ __launch_bounds__(512, 2) void k5a_gemm(
    const void* __restrict__ src, const void* __restrict__ nw,
    const float* __restrict__ ws,
    const ushort_t* __restrict__ ctxb, ushort_t* __restrict__ ybf)
{
    const ushort_t* woB = (const ushort_t*)(ws + OFF_WOT);
    const int isbf = get_isbf(nw);
    __shared__ __align__(16) ushort_t sB[384 * 72];   // 55296 B
    __shared__ __align__(16) ushort_t sA[32 * 72];    //  4608 B
    int j = threadIdx.x;
    int bx = blockIdx.x;
    int t0 = (bx >> 1) * 32;
    int colh = (bx & 1) * 384;
    int w = j >> 6, lane = j & 63;
    int tl = lane & 15, qd = lane >> 4;
    int mt = w & 1;
    int n0l = (w >> 1) * 96;          // wave's col offset within the 384

    f4_t acc[6];
#pragma unroll
    for (int nt = 0; nt < 6; ++nt) acc[nt] = (f4_t){0.f, 0.f, 0.f, 0.f};

    for (int kb = 0; kb < 12; ++kb) {
        __syncthreads();
        {   // stage B: wo rows colh..colh+383, cols kb*64..+63 (8 x uint4/row)
            for (int e = j; e < 384 * 8; e += 512) {
                int rr = e >> 3, ch = e & 7;
                uint4 v = *(const uint4*)(woB + (size_t)(colh + rr) * 768 + kb * 64 + ch * 8);
                *(uint4*)(sB + rr * 72 + ch * 8) = v;
            }
        }
        if (j < 256) {  // stage A: ctx rows t0..t0+31, cols kb*64..+63
            int rr = j >> 3, ch = j & 7;
            uint4 v = *(const uint4*)(ctxb + (size_t)(t0 + rr) * 768 + kb * 64 + ch * 8);
            *(uint4*)(sA + rr * 72 + ch * 8) = v;
        }
        __syncthreads();
        __builtin_amdgcn_s_setprio(1);
#pragma unroll
        for (int ks = 0; ks < 2; ++ks) {
            bf8_t a = *(const bf8_t*)(sA + (mt * 16 + tl) * 72 + ks * 32 + qd * 8);
#pragma unroll
            for (int nt = 0; nt < 6; ++nt) {
                bf8_t bfr = *(const bf8_t*)(sB + (n0l + nt * 16 + tl) * 72 + ks * 32 + qd * 8);
                acc[nt] = __builtin_amdgcn_mfma_f32_16x16x32_bf16(a, bfr, acc[nt], 0, 0, 0);
            }
        }
        __builtin_amdgcn_s_setprio(0);
    }
    // epilogue: residual add, store y bf16
#pragma unroll
    for (int nt = 0; nt < 6; ++nt)
#pragma unroll
        for (int r = 0; r < 4; ++r) {
            int row = t0 + mt * 16 + qd * 4 + r;
            int col = colh + n0l + nt * 16 + tl;
            float yv = acc[nt][r] + ldin(src, (size_t)row * 768 + col, isbf);
            ybf[(size_t)row * 768 + col] = f2bf(yv);
        }
}

// ---------------------------------------------------------------------------
// k5b: streaming RMSNorm y -> out. 16 tokens/block, grid 512, 256 thr.
// ---------------------------------------------------------------------------
__global__ __launch_bounds__(256) void k5b_norm(
    const void* __restrict__ nw_in, const float* __restrict__ ws,
    const ushort_t* __restrict__ ybf, void* __restrict__ out)
{
    const float* nw = ws + OFF_NW;
    const int isbf = get_isbf(nw_in);
    int j = threadIdx.x;
    int tt = j >> 4, s = j & 15;
    size_t row = (size_t)blockIdx.x * 16 + tt;
    const ushort_t* yp = ybf + row * 768 + s * 48;

    float val[48];
    float ss = 0.f;
#pragma unroll
    for (int c8 = 0; c8 < 6; ++c8) {
        union { uint4 u; ushort_t h[8]; } uu;
        uu.u = ((const uint4*)yp)[c8];
#pragma unroll
        for (int c = 0; c < 8; ++c) {
            float v = bf2f(uu.h[c]);
            val[c8 * 8 + c] = v;
            ss += v * v;
        }
    }
    ss += __shfl_xor(ss, 1); ss += __shfl_xor(ss, 2);
    ss += __shfl_xor(ss, 4); ss += __shfl_xor(ss, 8);
    float rs = rsqrtf(ss * (1.f / 768.f) + EPSF);
    const float* nwp = nw + s * 48;
    size_t base = row * 768 + s * 48;
    if (isbf) {
        ushort_t* op = (ushort_t*)out + base;
#pragma unroll
        for (int c8 = 0; c8 < 6; ++c8) {
            union { uint4 u; ushort_t h[8]; } uu;
#pragma unroll
            for (int c = 0; c < 8; ++c) {
                float hv = bf2f(f2bf(val[c8 * 8 + c] * rs));
                uu.h[c] = f2bf(hv * nwp[c8 * 8 + c]);
            }
            ((uint4*)op)[c8] = uu.u;
        }
    } else {
        float* op = (float*)out + base;
#pragma unroll
        for (int c4 = 0; c4 < 12; ++c4) {
            float4 f;
            f.x = val[c4 * 4 + 0] * rs * nwp[c4 * 4 + 0];
            f.y = val[c4 * 4 + 1] * rs * nwp[c4 * 4 + 1];
            f.z = val[c4 * 4 + 2] * rs * nwp[c4 * 4 + 2];
            f.w = val[c4 * 4 + 3] * rs * nwp[c4 * 4 + 3];
            ((float4*)op)[c4] = f;
        }
    }
}

// ---------------------------------------------------------------------------
extern "C" void kernel_launch(void* const* d_in, const int* in_sizes, int n_in,
                              void* d_out, int out_size, void* d_ws, size_t ws_size,
                              hipStream_t stream)
{
    const void* src   = d_in[0];
    const void* wq_a  = d_in[1];
    const void* q_ln  = d_in[2];
    const void* wq_b  = d_in[3];
    const void* wkv_a = d_in[4];
    const void* kv_ln = d_in[5];
    const void* wkv_b = d_in[6];
    const void* wo    = d_in[7];
    const void* nw    = d_in[8];
    float* ws = (float*)d_ws;
    ushort_t* Kbf   = (ushort_t*)(ws + OFF_KBF);
    ushort_t* VTbf  = (ushort_t*)(ws + OFF_VTB);
    ushort_t* Qbf   = (ushort_t*)(ws + OFF_QBF);
    ushort_t* ctxb  = (ushort_t*)(ws + OFF_CTXF);
    ushort_t* oaTb  = (ushort_t*)(ws + OFF_OATB);
    ushort_t* ybf   = Qbf;   // Q' dead after k3; reuse as y [8192][768]
    ushort_t* qn    = ctxb;  // ctx region dead until k3; reuse as qn [8192][64]

    prep_k<<<dim3(PB7), dim3(256), 0, stream>>>(wq_a, q_ln, wq_b, wkv_a, kv_ln, wkv_b, wo, nw, ws);
    k1_ckv<<<dim3(TOK / 32), dim3(512), 0, stream>>>(src, nw, ws, Kbf, VTbf, qn);
    k2b_q<<<dim3(TOK / 32 * 2), dim3(512), 0, stream>>>(ws, qn, Qbf);
    k3_attn<<<dim3(16, 8, 4), dim3(256), 0, stream>>>(Qbf, Kbf, VTbf, oaTb, ctxb);
    k5a_gemm<<<dim3(TOK / 32 * 2), dim3(512), 0, stream>>>(src, nw, ws, ctxb, ybf);
    k5b_norm<<<dim3(TOK / 16), dim3(256), 0, stream>>>(nw, ws, ybf, d_out);
}